// Round 7
// baseline (629.774 us; speedup 1.0000x reference)
//
#include <hip/hip_runtime.h>
#include <stdint.h>

// ---------------------------------------------------------------------------
// ModifiedSelfAttention (Wan block): QKV GEMM -> RMSNorm+RoPE -> flash attn -> O GEMM
// R8: R6 attn math/pipeline exactly (KVBLK=64 dbuf, vmcnt(4), KSPLIT=2,
//     32x32 MFMA, in-reg P), repackaged as 512-thread blocks (8 waves x 32q
//     = 256 q/block): grid 360 <= residency capacity -> ENTIRE grid
//     co-resident (no rounds, no tail), 11.25 waves/CU vs R6's 8.
//     Staging amortized 8 ways; Opart 47MB written in one end-burst.
// ---------------------------------------------------------------------------

#define DIM   1536
#define S_TOT 3744
#define NHEAD 12
#define HD    128
#define QTB   15          // q-tiles per head (256 q per block; 3744=14*256+160)
#define KVT   59          // key tiles of 64 (ceil(3744/64))
#define KSPLIT 2          // split-K factor (tiles [0,30) / [30,59))

using short8 = __attribute__((ext_vector_type(8))) short;   // 8 bf16 (4 VGPRs)
using f32x4  = __attribute__((ext_vector_type(4))) float;   // 16x16 MFMA C/D
using f32x16 = __attribute__((ext_vector_type(16))) float;  // 32x32 MFMA C/D
using f32x2  = __attribute__((ext_vector_type(2))) float;

__device__ __forceinline__ unsigned short f2bf(float f) {
  unsigned u = __builtin_bit_cast(unsigned, f);
  u += 0x7fffu + ((u >> 16) & 1u);     // RNE
  return (unsigned short)(u >> 16);
}

__device__ __forceinline__ short8 mk8(unsigned a, unsigned b, unsigned c, unsigned d) {
  union { unsigned u[4]; short8 s; } x;
  x.u[0] = a; x.u[1] = b; x.u[2] = c; x.u[3] = d;
  return x.s;
}

// async global->LDS, 16B per lane. LDS dest must be wave-uniform base + lane*16.
__device__ __forceinline__ void gl_lds16(const void* g, void* l) {
  auto gp = (const __attribute__((address_space(1))) unsigned int*)g;
  auto lp = (__attribute__((address_space(3))) unsigned int*)(uintptr_t)l;
  __builtin_amdgcn_global_load_lds(gp, lp, 16, 0, 0);
}

// ---------------------------------------------------------------------------
// fp32 -> bf16 convert, all 5 arrays in one launch
// ---------------------------------------------------------------------------
#define NX4 (S_TOT * DIM / 4)
#define NW4 (DIM * DIM / 4)
__global__ __launch_bounds__(256) void cvt5_kernel(
    const float* __restrict__ x, const float* __restrict__ wq,
    const float* __restrict__ wk, const float* __restrict__ wv,
    const float* __restrict__ wo,
    unsigned short* __restrict__ xb, unsigned short* __restrict__ wqb,
    unsigned short* __restrict__ wkb, unsigned short* __restrict__ wvb,
    unsigned short* __restrict__ wob) {
  int gid = blockIdx.x * 256 + threadIdx.x;
  const float* src; unsigned short* dst; int off;
  if (gid < NX4)                { src = x;  dst = xb;  off = gid; }
  else if (gid < NX4 + NW4)     { src = wq; dst = wqb; off = gid - NX4; }
  else if (gid < NX4 + 2 * NW4) { src = wk; dst = wkb; off = gid - NX4 - NW4; }
  else if (gid < NX4 + 3 * NW4) { src = wv; dst = wvb; off = gid - NX4 - 2 * NW4; }
  else if (gid < NX4 + 4 * NW4) { src = wo; dst = wob; off = gid - NX4 - 3 * NW4; }
  else return;
  float4 v = ((const float4*)src)[off];
  ushort4 o;
  o.x = f2bf(v.x); o.y = f2bf(v.y); o.z = f2bf(v.z); o.w = f2bf(v.w);
  ((ushort4*)dst)[off] = o;
}

// ---------------------------------------------------------------------------
// NT GEMM: C[m,n] = sum_k A[m,k]*W[n,k] + bias[n]. m97 structure (unchanged, proven).
// ---------------------------------------------------------------------------
__device__ __forceinline__ void gemm_body(const unsigned short* __restrict__ A,
                                          const unsigned short* __restrict__ W,
                                          const float* __restrict__ bias,
                                          float* __restrict__ outF,
                                          unsigned short* __restrict__ outB,
                                          int M, int mode) {
  constexpr int K = DIM, N = DIM;
  __shared__ unsigned short As[128 * 32];
  __shared__ unsigned short Ws[128 * 32];
  int tid = threadIdx.x;
  int w = tid >> 6, lane = tid & 63;
  int wr = w >> 1, wc = w & 1, q4 = lane >> 4, ql = lane & 15;
  int m0 = blockIdx.y * 128, n0 = blockIdx.x * 128;

  f32x4 acc[4][4];
  const f32x4 zero4 = {0.f, 0.f, 0.f, 0.f};
#pragma unroll
  for (int i = 0; i < 4; i++)
#pragma unroll
    for (int j = 0; j < 4; j++) acc[i][j] = zero4;

  for (int k0 = 0; k0 < K; k0 += 32) {
    __syncthreads();
#pragma unroll
    for (int r = 0; r < 2; r++) {
      int idx = r * 256 + tid;
      int row = idx >> 2, ch = idx & 3;
      int am = m0 + row; am = (am < M) ? am : (M - 1);
      gl_lds16(A + (size_t)am * K + k0 + ch * 8, &As[idx * 8]);
      gl_lds16(W + (size_t)(n0 + row) * K + k0 + ch * 8, &Ws[idx * 8]);
    }
    __syncthreads();
    short8 af[4], wf[4];
#pragma unroll
    for (int i = 0; i < 4; i++)
      af[i] = *(const short8*)&As[(wr * 64 + i * 16 + ql) * 32 + q4 * 8];
#pragma unroll
    for (int j = 0; j < 4; j++)
      wf[j] = *(const short8*)&Ws[(wc * 64 + j * 16 + ql) * 32 + q4 * 8];
#pragma unroll
    for (int i = 0; i < 4; i++)
#pragma unroll
      for (int j = 0; j < 4; j++)
        acc[i][j] = __builtin_amdgcn_mfma_f32_16x16x32_bf16(af[i], wf[j], acc[i][j], 0, 0, 0);
  }

  float bb[4];
#pragma unroll
  for (int j = 0; j < 4; j++) bb[j] = bias[n0 + wc * 64 + j * 16 + ql];
#pragma unroll
  for (int i = 0; i < 4; i++) {
#pragma unroll
    for (int rg = 0; rg < 4; rg++) {
      int row = m0 + wr * 64 + i * 16 + q4 * 4 + rg;
      if (row < M) {
#pragma unroll
        for (int j = 0; j < 4; j++) {
          int col = n0 + wc * 64 + j * 16 + ql;
          float v = acc[i][j][rg] + bb[j];
          if (mode == 0) outF[(size_t)row * N + col] = v;
          else           outB[(size_t)row * N + col] = f2bf(v);
        }
      }
    }
  }
}

__global__ __launch_bounds__(256) void gemm_qkv_kernel(
    const unsigned short* __restrict__ xb,
    const unsigned short* __restrict__ wqb, const unsigned short* __restrict__ wkb,
    const unsigned short* __restrict__ wvb,
    const float* __restrict__ bq, const float* __restrict__ bk, const float* __restrict__ bv,
    float* __restrict__ Yq, float* __restrict__ Yk, unsigned short* __restrict__ Vb) {
  int z = blockIdx.z;
  const unsigned short* W = (z == 0) ? wqb : ((z == 1) ? wkb : wvb);
  const float* bias       = (z == 0) ? bq  : ((z == 1) ? bk  : bv);
  float* outF             = (z == 0) ? Yq  : Yk;
  gemm_body(xb, W, bias, outF, Vb, S_TOT, (z == 2) ? 1 : 0);
}

__global__ __launch_bounds__(256) void gemm_out_kernel(
    const unsigned short* __restrict__ AO, const unsigned short* __restrict__ wob,
    const float* __restrict__ bo, float* __restrict__ out) {
  gemm_body(AO, wob, bo, out, nullptr, S_TOT, 0);
}

// ---------------------------------------------------------------------------
// RMSNorm + RoPE. Q pre-scaled by sm_scale*log2(e) -> attn softmax runs in
// exp2 domain with no per-score multiply (rotation is linear -> commutes).
// ---------------------------------------------------------------------------
__global__ __launch_bounds__(256) void normrope_kernel(
    const float* __restrict__ Yq, const float* __restrict__ Yk,
    const float* __restrict__ gq, const float* __restrict__ gk,
    const float* __restrict__ freqs,
    unsigned short* __restrict__ Qb, unsigned short* __restrict__ Kb) {
  int s = blockIdx.x;
  int tid = threadIdx.x;
  int w = tid >> 6, lane = tid & 63;
  const f32x2* yq2 = (const f32x2*)(Yq + (size_t)s * DIM);
  const f32x2* yk2 = (const f32x2*)(Yk + (size_t)s * DIM);
  f32x2 vq[3], vk[3];
  float ssq = 0.f, ssk = 0.f;
#pragma unroll
  for (int r = 0; r < 3; r++) {
    int p = tid + 256 * r;
    vq[r] = yq2[p]; vk[r] = yk2[p];
    ssq += vq[r].x * vq[r].x + vq[r].y * vq[r].y;
    ssk += vk[r].x * vk[r].x + vk[r].y * vk[r].y;
  }
#pragma unroll
  for (int d = 1; d < 64; d <<= 1) {
    ssq += __shfl_xor(ssq, d);
    ssk += __shfl_xor(ssk, d);
  }
  __shared__ float rq[4], rk[4];
  if (lane == 0) { rq[w] = ssq; rk[w] = ssk; }
  __syncthreads();
  float tq = rq[0] + rq[1] + rq[2] + rq[3];
  float tk = rk[0] + rk[1] + rk[2] + rk[3];
  const float SM_L2 = 0.08838834764831845f * 1.4426950408889634f; // scale*log2e
  float invq = rsqrtf(tq * (1.f / DIM) + 1e-6f) * SM_L2;
  float invk = rsqrtf(tk * (1.f / DIM) + 1e-6f);

  int fi = s / (26 * 48);
  int hi = (s / 48) % 26;
  int wi = s % 48;
#pragma unroll
  for (int r = 0; r < 3; r++) {
    int p = tid + 256 * r;
    int c = p & 63;
    int frow = (c < 22) ? fi : ((c < 43) ? hi : wi);
    float ang = freqs[frow * 64 + c];
    float sn, cs;
    __sincosf(ang, &sn, &cs);
    {
      float a = vq[r].x * invq * gq[2 * p];
      float b = vq[r].y * invq * gq[2 * p + 1];
      ushort2 o; o.x = f2bf(a * cs - b * sn); o.y = f2bf(a * sn + b * cs);
      ((ushort2*)Qb)[(size_t)s * (DIM / 2) + p] = o;
    }
    {
      float a = vk[r].x * invk * gk[2 * p];
      float b = vk[r].y * invk * gk[2 * p + 1];
      ushort2 o; o.x = f2bf(a * cs - b * sn); o.y = f2bf(a * sn + b * cs);
      ((ushort2*)Kb)[(size_t)s * (DIM / 2) + p] = o;
    }
  }
}

// ---------------------------------------------------------------------------
// V transpose (unchanged, proven)
// ---------------------------------------------------------------------------
__global__ __launch_bounds__(256) void vtrans_kernel(const unsigned short* __restrict__ Vb,
                                                     unsigned short* __restrict__ Vt) {
  int d0 = blockIdx.x * 64, s0 = blockIdx.y * 64;
  __shared__ unsigned short t[64][65];
  int tid = threadIdx.x;
#pragma unroll
  for (int r = 0; r < 4; r++) {
    int idx = r * 256 + tid;
    int sr = idx >> 4, c4 = (idx & 15) * 4;
    ushort4 v; v.x = v.y = v.z = v.w = 0;
    int s = s0 + sr;
    if (s < S_TOT) v = *(const ushort4*)(Vb + (size_t)s * DIM + d0 + c4);
    t[sr][c4 + 0] = v.x; t[sr][c4 + 1] = v.y; t[sr][c4 + 2] = v.z; t[sr][c4 + 3] = v.w;
  }
  __syncthreads();
#pragma unroll
  for (int r = 0; r < 4; r++) {
    int idx = r * 256 + tid;
    int dr = idx >> 4, s4 = (idx & 15) * 4;
    if (s0 + s4 < S_TOT) {
      ushort4 v;
      v.x = t[s4 + 0][dr]; v.y = t[s4 + 1][dr]; v.z = t[s4 + 2][dr]; v.w = t[s4 + 3][dr];
      *(ushort4*)(Vt + (size_t)(d0 + dr) * S_TOT + s0 + s4) = v;
    }
  }
}

// ---------------------------------------------------------------------------
// Flash attention v9: 32x32x16 MFMA, in-register P, 8 waves x 32q = 256q/block,
// double-buffered K/V (KVBLK=64) with counted vmcnt(4), split-K=2.
// Grid 360 <= 2-blocks/CU capacity -> whole grid co-resident, no tail.
// Per wave per tile:
//   QK^T: S^T = mfma(A=K[32k x 16d], B=Q[16d x 32q]) x8 d-slices x2 key-halves
//   softmax: in-lane (q = lane&31), 1 shfl_xor(32); defer-max (T13, THR=8)
//   P->bf16 A-frags: v_cvt_pk_bf16_f32 + v_permlane32_swap_b32 (in-register)
//   PV: O += mfma(A=P, B=V[16k x 32d]) x4 key-slices x4 d-quarters
// K LDS [64][128] chunk-swizzle c^(row&15); V LDS [128][64] c^(row&7).
// LDS = 2*(16K+16K) = 64 KB. Emits unnormalized O f32 + (m,l); reduce combines.
// ---------------------------------------------------------------------------
__global__ __launch_bounds__(512, 4) void attn_kernel(
    const unsigned short* __restrict__ Qb, const unsigned short* __restrict__ Kb,
    const unsigned short* __restrict__ Vt,
    float* __restrict__ Opart, float2* __restrict__ Ml,
    const int* __restrict__ seq_lens) {
  // bijective XCD-chunked remap (T1/m204): 360 % 8 == 0 -> chunks of 45
  // (= 3 full (h,split) K/V groups of ~1MB per XCD L2).
  const int NWG = QTB * NHEAD * KSPLIT;    // 360
  int bid = blockIdx.x;
  int xcd = bid & 7, bix = bid >> 3;
  const int qc = NWG >> 3;                 // 45
  int wg = xcd * qc + bix;
  int qt  = wg % QTB;
  int rem = wg / QTB;                      // 0..23, consecutive share (h,split)
  int h    = rem >> 1;
  int sidx = rem & 1;
  int tbeg = sidx ? 30 : 0;
  int tend = sidx ? KVT : 30;

  int tid = threadIdx.x;                   // 0..511
  int wv = tid >> 6, lane = tid & 63;
  int lo = lane & 31, hf = lane >> 5;
  int seqlen = seq_lens[0]; if (seqlen > S_TOT) seqlen = S_TOT;

  __shared__ unsigned short Kl[2][64 * 128];  // 2 x 16 KB, chunk-swizzled
  __shared__ unsigned short Vl[2][128 * 64];  // 2 x 16 KB, chunk-swizzled

  int q0 = qt * 256 + wv * 32;
  bool wact = (q0 < S_TOT);                // tail tile: waves 5..7 idle
  const size_t hoff = (size_t)h * HD;

  // staging (per tile): K 64 rows x 16 chunks + V 128 rows x 8 chunks,
  // 2+2 gl_lds per thread (512 threads). Slot c holds chunk c^(row&mask).
  auto stage = [&](int buf, int t) {
    int k0 = t * 64;
    const unsigned short* kseg = Kb + (size_t)k0 * DIM + hoff;
#pragma unroll
    for (int r = 0; r < 2; r++) {
      int idx = r * 512 + tid;
      int row = idx >> 4, c = idx & 15;
      int g = c ^ (row & 15);
      gl_lds16(kseg + (size_t)row * DIM + g * 8, &Kl[buf][idx * 8]);
    }
    int kmax = S_TOT - 8 - k0;             // clamp key-chunk start (last tile)
#pragma unroll
    for (int r = 0; r < 2; r++) {
      int idx = r * 512 + tid;
      int row = idx >> 3, c = idx & 7;
      int g = c ^ (row & 7);
      int kc = g * 8; if (kc > kmax) kc = kmax;
      gl_lds16(Vt + (hoff + row) * S_TOT + k0 + kc, &Vl[buf][idx * 8]);
    }
  };

  // Q B-frags (hoisted): qf[ks] = Q[q0+lo][ks*16 + hf*8 .. +7]
  short8 qf[8];
  {
    int qrow = q0 + lo; if (qrow > S_TOT - 1) qrow = S_TOT - 1;
#pragma unroll
    for (int ks = 0; ks < 8; ks++)
      qf[ks] = *(const short8*)(Qb + (size_t)qrow * DIM + hoff + ks * 16 + hf * 8);
  }
  asm volatile("s_waitcnt vmcnt(0)" ::: "memory");  // Q landed; vmcnt clean

  f32x16 o[4];
#pragma unroll
  for (int dq = 0; dq < 4; dq++)
#pragma unroll
    for (int r = 0; r < 16; r++) o[dq][r] = 0.f;
  float m_run = -3.0e38f, l_run = 0.f;

  stage(0, tbeg);                          // prologue: first tile in flight

  for (int t = tbeg; t < tend; ++t) {
    int cur = (t - tbeg) & 1;
    int k0 = t * 64;
    __builtin_amdgcn_s_barrier();          // all reads of buf[cur^1] done
    asm volatile("" ::: "memory");
    if (t + 1 < tend) {
      stage(cur ^ 1, t + 1);               // prefetch next tile (4 gl_lds/thr)
      asm volatile("s_waitcnt vmcnt(4)" ::: "memory");   // tile t landed (mine)
    } else {
      asm volatile("s_waitcnt vmcnt(0)" ::: "memory");
    }
    __builtin_amdgcn_sched_barrier(0);
    __builtin_amdgcn_s_barrier();          // tile t landed (everyone)
    asm volatile("" ::: "memory");
    if (!wact) continue;

    // ---- QK^T: two 32-key halves, dual accumulation chains ----
    f32x16 s0, s1;
#pragma unroll
    for (int r = 0; r < 16; r++) { s0[r] = 0.f; s1[r] = 0.f; }
    __builtin_amdgcn_s_setprio(1);
#pragma unroll
    for (int ks = 0; ks < 8; ks++) {
      int sl = ((ks * 2 + hf) ^ (lo & 15)) * 8;
      short8 kf0 = *(const short8*)&Kl[cur][lo * 128 + sl];
      short8 kf1 = *(const short8*)&Kl[cur][(32 + lo) * 128 + sl];
      s0 = __builtin_amdgcn_mfma_f32_32x32x16_bf16(kf0, qf[ks], s0, 0, 0, 0);
      s1 = __builtin_amdgcn_mfma_f32_32x32x16_bf16(kf1, qf[ks], s1, 0, 0, 0);
    }
    __builtin_amdgcn_s_setprio(0);

    // ---- mask (ragged last tile only) ----
    if (k0 + 64 > seqlen) {
#pragma unroll
      for (int r = 0; r < 16; r++) {
        int key0 = k0 + (r & 3) + 8 * (r >> 2) + 4 * hf;
        if (key0      >= seqlen) s0[r] = -3.0e38f;
        if (key0 + 32 >= seqlen) s1[r] = -3.0e38f;
      }
    }

    // ---- online softmax (exp2 domain; Q pre-scaled) ----
    float mloc = s0[0];
#pragma unroll
    for (int r = 1; r < 16; r++) mloc = fmaxf(mloc, s0[r]);
#pragma unroll
    for (int r = 0; r < 16; r++) mloc = fmaxf(mloc, s1[r]);
    mloc = fmaxf(mloc, __shfl_xor(mloc, 32));

    // defer-max (T13): rescale only when growth > 8 (rare); alpha needs a
    // lane->reg-row redistribution (q=lane&31 -> q=(r&3)+8*(r>>2)+4*hf)
    if (!__all(mloc <= m_run + 8.0f)) {
      float mnew = fmaxf(m_run, mloc);
      float alpha = exp2f(m_run - mnew);   // 0 on first tile
      m_run = mnew;
      l_run *= alpha;
      int lb = lane & 32;
      float ar[16];
#pragma unroll
      for (int r = 0; r < 16; r++)
        ar[r] = __shfl(alpha, ((r & 3) + 8 * (r >> 2) + 4 * hf) | lb);
#pragma unroll
      for (int dq = 0; dq < 4; dq++)
#pragma unroll
        for (int r = 0; r < 16; r++) o[dq][r] *= ar[r];
    }

    // ---- P = exp2(s - m) -> bf16 A-frags fully in-register (T12) ----
    float lloc = 0.f;
    short8 pa[4];
    {
      float p[16];
#pragma unroll
      for (int r = 0; r < 16; r++) { p[r] = exp2f(s0[r] - m_run); lloc += p[r]; }
      unsigned pr[8];
#pragma unroll
      for (int i = 0; i < 8; i++)
        asm("v_cvt_pk_bf16_f32 %0, %1, %2" : "=v"(pr[i]) : "v"(p[2 * i]), "v"(p[2 * i + 1]));
      asm volatile("v_permlane32_swap_b32 %0, %1" : "+v"(pr[0]), "+v"(pr[2]));
      asm volatile("v_permlane32_swap_b32 %0, %1" : "+v"(pr[1]), "+v"(pr[3]));
      asm volatile("v_permlane32_swap_b32 %0, %1" : "+v"(pr[4]), "+v"(pr[6]));
      asm volatile("v_permlane32_swap_b32 %0, %1" : "+v"(pr[5]), "+v"(pr[7]));
      pa[0] = mk8(pr[0], pr[1], pr[2], pr[3]);
      pa[1] = mk8(pr[4], pr[5], pr[6], pr[7]);
    }
    {
      float p[16];
#pragma unroll
      for (int r = 0; r < 16; r++) { p[r] = exp2f(s1[r] - m_run); lloc += p[r]; }
      unsigned pr[8];
#pragma unroll
      for (int i = 0; i < 8; i++)
        asm("v_cvt_pk_bf16_f32 %0, %1, %2" : "=v"(pr[i]) : "v"(p[2 * i]), "v"(p[2 * i + 1]));
      asm volatile("v_permlane32_swap_b32 %0, %1" : "+v"(pr[0]), "+v"(pr[2]));
      asm volatile("v_permlane32_swap_b32 %0, %1" : "+v"(pr[1]), "+v"(pr[3]));
      asm volatile("v_permlane32_swap_b32 %0, %1" : "+v"(pr[4]), "+v"(pr[6]));
      asm volatile("v_permlane32_swap_b32 %0, %1" : "+v"(pr[5]), "+v"(pr[7]));
      pa[2] = mk8(pr[0], pr[1], pr[2], pr[3]);
      pa[3] = mk8(pr[4], pr[5], pr[6], pr[7]);
    }
    lloc += __shfl_xor(lloc, 32);
    l_run += lloc;

    // ---- PV: O[q][d] += P.V, 4 independent acc chains ----
    __builtin_amdgcn_s_setprio(1);
#pragma unroll
    for (int kh2 = 0; kh2 < 4; kh2++) {
      int sl = ((kh2 * 2 + hf) ^ (lo & 7)) * 8;
#pragma unroll
      for (int dq = 0; dq < 4; dq++) {
        short8 vb = *(const short8*)&Vl[cur][(dq * 32 + lo) * 64 + sl];
        o[dq] = __builtin_amdgcn_mfma_f32_32x32x16_bf16(pa[kh2], vb, o[dq], 0, 0, 0);
      }
    }
    __builtin_amdgcn_s_setprio(0);
  }

  if (wact) {
    // unnormalized partials: O f32 [256 q][128 d] + (m,l) per q-row
    size_t ob = (((size_t)sidx * NHEAD + h) * QTB + qt) * (256 * 128);
#pragma unroll
    for (int dq = 0; dq < 4; dq++)
#pragma unroll
      for (int r = 0; r < 16; r++) {
        int row = wv * 32 + (r & 3) + 8 * (r >> 2) + 4 * hf;
        Opart[ob + (size_t)row * 128 + dq * 32 + lo] = o[dq][r];
      }
    if (lane < 32) {
      float2 ml; ml.x = m_run; ml.y = l_run;
      Ml[((size_t)(sidx * NHEAD + h) * QTB + qt) * 256 + wv * 32 + lo] = ml;
    }
  }
}

// ---------------------------------------------------------------------------
// split-K reduce: AO[q, h*HD+d] = sum_s w_s O_s / sum_s w_s l_s,
// w_s = exp2(m_s - max_s m_s). Grid exact: NHEAD*S_TOT*HD / 256 = 22464.
// ---------------------------------------------------------------------------
__global__ __launch_bounds__(256) void reduce_kernel(
    const float* __restrict__ Opart, const float2* __restrict__ Ml,
    unsigned short* __restrict__ AO) {
  int flat = blockIdx.x * 256 + threadIdx.x;
  int d = flat & 127;
  int r = flat >> 7;                       // 0 .. NHEAD*S_TOT-1
  int h = r / S_TOT;
  int q = r - h * S_TOT;
  int qt = q >> 8, qi = q & 255;
  size_t ob = (((size_t)h * QTB) + qt) * (256 * 128) + (size_t)qi * 128 + d;
  const size_t so = (size_t)NHEAD * QTB * 256 * 128;
  int mb = (h * QTB + qt) * 256 + qi;
  const int sm = NHEAD * QTB * 256;
  float2 ml0 = Ml[mb], ml1 = Ml[mb + sm];
  float mm = fmaxf(ml0.x, ml1.x);
  float w0 = exp2f(ml0.x - mm), w1 = exp2f(ml1.x - mm);
  float l = w0 * ml0.y + w1 * ml1.y;
  float v = (w0 * Opart[ob] + w1 * Opart[ob + so]) / l;
  AO[(size_t)q * DIM + h * HD + d] = f2bf(v);
}

// ---------------------------------------------------------------------------
extern "C" void kernel_launch(void* const* d_in, const int* in_sizes, int n_in,
                              void* d_out, int out_size, void* d_ws, size_t ws_size,
                              hipStream_t stream) {
  const float* x    = (const float*)d_in[0];
  const float* wq   = (const float*)d_in[1];
  const float* bq   = (const float*)d_in[2];
  const float* wk   = (const float*)d_in[3];
  const float* bk   = (const float*)d_in[4];
  const float* wv   = (const float*)d_in[5];
  const float* bv   = (const float*)d_in[6];
  const float* wo   = (const float*)d_in[7];
  const float* bo   = (const float*)d_in[8];
  const float* gq   = (const float*)d_in[9];
  const float* gk   = (const float*)d_in[10];
  const float* freqs = (const float*)d_in[11];
  const int*   seq  = (const int*)d_in[12];

  char* ws = (char*)d_ws;
  const size_t SZ_X = (size_t)S_TOT * DIM * 2;   // bf16 [S,DIM]
  const size_t SZ_W = (size_t)DIM * DIM * 2;     // bf16 [DIM,DIM]
  const size_t SZ_Y = (size_t)S_TOT * DIM * 4;   // fp32 [S,DIM]

  // Layout: Yq..wvb (2*SZ_Y + 3*SZ_W = 60.2 MB) dead after normrope -> reused
  // for split-K partials (47.2 MB). Ml (1.5 MB) reuses dead xb region.
  size_t off = 0;
  unsigned short* xb  = (unsigned short*)(ws + off); off += SZ_X;
  unsigned short* wob = (unsigned short*)(ws + off); off += SZ_W;
  float*          Yq  = (float*)(ws + off);          off += SZ_Y;
  float*          Yk  = (float*)(ws + off);          off += SZ_Y;
  unsigned short* wqb = (unsigned short*)(ws + off); off += SZ_W;
  unsigned short* wkb = (unsigned short*)(ws + off); off += SZ_W;
  unsigned short* wvb = (unsigned short*)(ws + off); off += SZ_W;
  unsigned short* Vb  = (unsigned short*)(ws + off); off += SZ_X;
  unsigned short* Qb  = (unsigned short*)(ws + off); off += SZ_X;
  unsigned short* Kb  = (unsigned short*)(ws + off); off += SZ_X;
  unsigned short* Vt  = (unsigned short*)(ws + off); off += SZ_X;
  unsigned short* AO  = (unsigned short*)(ws + off); off += SZ_X;

  float*  Opart = (float*)Yq;            // 2*12*15*256*128*4 = 47.2 MB
  float2* Ml    = (float2*)xb;           // 2*12*15*256*8     = 1.47 MB

  int total4 = NX4 + 4 * NW4;
  cvt5_kernel<<<dim3((total4 + 255) / 256), 256, 0, stream>>>(
      x, wq, wk, wv, wo, xb, wqb, wkb, wvb, wob);

  gemm_qkv_kernel<<<dim3(DIM / 128, (S_TOT + 127) / 128, 3), 256, 0, stream>>>(
      xb, wqb, wkb, wvb, bq, bk, bv, Yq, Yk, Vb);

  normrope_kernel<<<dim3(S_TOT), 256, 0, stream>>>(Yq, Yk, gq, gk, freqs, Qb, Kb);

  vtrans_kernel<<<dim3(DIM / 64, (S_TOT + 63) / 64), 256, 0, stream>>>(Vb, Vt);

  attn_kernel<<<dim3(QTB * NHEAD * KSPLIT), 512, 0, stream>>>(
      Qb, Kb, Vt, Opart, Ml, seq);

  reduce_kernel<<<dim3(NHEAD * S_TOT * HD / 256), 256, 0, stream>>>(Opart, Ml, AO);

  gemm_out_kernel<<<dim3(DIM / 128, (S_TOT + 127) / 128), 256, 0, stream>>>(
      AO, wob, bo, (float*)d_out);
}

// Round 8
// 445.177 us; speedup vs baseline: 1.4147x; 1.4147x over previous
//
#include <hip/hip_runtime.h>
#include <stdint.h>

// ---------------------------------------------------------------------------
// ModifiedSelfAttention (Wan block): QKV GEMM -> RMSNorm+RoPE -> flash attn -> O GEMM
// R9: R6 restored (256-thr/4-wave blocks, KVBLK=64, KSPLIT=2, grid 720 —
//     the config with verified L2 locality, FETCH 23MB), plus:
//   - V single-buffered (staged at tile top, lands under QK^T+softmax),
//     K double-buffered -> LDS 48KB -> 3 blocks/CU (12 waves/CU cap, was 8)
//   - vmcnt choreography: issue V(t) then K(t+1); drain K(t)=vmcnt(4),
//     drain V(t)=vmcnt(2); 3 barriers/tile; tail waves keep barrier parity.
// ---------------------------------------------------------------------------

#define DIM   1536
#define S_TOT 3744
#define NHEAD 12
#define HD    128
#define QT2   30          // q-tiles per head (128 q per block)
#define KVT   59          // key tiles of 64 (ceil(3744/64))
#define KSPLIT 2          // split-K factor (tiles [0,30) / [30,59))

using short8 = __attribute__((ext_vector_type(8))) short;   // 8 bf16 (4 VGPRs)
using f32x4  = __attribute__((ext_vector_type(4))) float;   // 16x16 MFMA C/D
using f32x16 = __attribute__((ext_vector_type(16))) float;  // 32x32 MFMA C/D
using f32x2  = __attribute__((ext_vector_type(2))) float;

__device__ __forceinline__ unsigned short f2bf(float f) {
  unsigned u = __builtin_bit_cast(unsigned, f);
  u += 0x7fffu + ((u >> 16) & 1u);     // RNE
  return (unsigned short)(u >> 16);
}

__device__ __forceinline__ short8 mk8(unsigned a, unsigned b, unsigned c, unsigned d) {
  union { unsigned u[4]; short8 s; } x;
  x.u[0] = a; x.u[1] = b; x.u[2] = c; x.u[3] = d;
  return x.s;
}

// async global->LDS, 16B per lane. LDS dest must be wave-uniform base + lane*16.
__device__ __forceinline__ void gl_lds16(const void* g, void* l) {
  auto gp = (const __attribute__((address_space(1))) unsigned int*)g;
  auto lp = (__attribute__((address_space(3))) unsigned int*)(uintptr_t)l;
  __builtin_amdgcn_global_load_lds(gp, lp, 16, 0, 0);
}

// ---------------------------------------------------------------------------
// fp32 -> bf16 convert, all 5 arrays in one launch
// ---------------------------------------------------------------------------
#define NX4 (S_TOT * DIM / 4)
#define NW4 (DIM * DIM / 4)
__global__ __launch_bounds__(256) void cvt5_kernel(
    const float* __restrict__ x, const float* __restrict__ wq,
    const float* __restrict__ wk, const float* __restrict__ wv,
    const float* __restrict__ wo,
    unsigned short* __restrict__ xb, unsigned short* __restrict__ wqb,
    unsigned short* __restrict__ wkb, unsigned short* __restrict__ wvb,
    unsigned short* __restrict__ wob) {
  int gid = blockIdx.x * 256 + threadIdx.x;
  const float* src; unsigned short* dst; int off;
  if (gid < NX4)                { src = x;  dst = xb;  off = gid; }
  else if (gid < NX4 + NW4)     { src = wq; dst = wqb; off = gid - NX4; }
  else if (gid < NX4 + 2 * NW4) { src = wk; dst = wkb; off = gid - NX4 - NW4; }
  else if (gid < NX4 + 3 * NW4) { src = wv; dst = wvb; off = gid - NX4 - 2 * NW4; }
  else if (gid < NX4 + 4 * NW4) { src = wo; dst = wob; off = gid - NX4 - 3 * NW4; }
  else return;
  float4 v = ((const float4*)src)[off];
  ushort4 o;
  o.x = f2bf(v.x); o.y = f2bf(v.y); o.z = f2bf(v.z); o.w = f2bf(v.w);
  ((ushort4*)dst)[off] = o;
}

// ---------------------------------------------------------------------------
// NT GEMM: C[m,n] = sum_k A[m,k]*W[n,k] + bias[n]. m97 structure (unchanged, proven).
// ---------------------------------------------------------------------------
__device__ __forceinline__ void gemm_body(const unsigned short* __restrict__ A,
                                          const unsigned short* __restrict__ W,
                                          const float* __restrict__ bias,
                                          float* __restrict__ outF,
                                          unsigned short* __restrict__ outB,
                                          int M, int mode) {
  constexpr int K = DIM, N = DIM;
  __shared__ unsigned short As[128 * 32];
  __shared__ unsigned short Ws[128 * 32];
  int tid = threadIdx.x;
  int w = tid >> 6, lane = tid & 63;
  int wr = w >> 1, wc = w & 1, q4 = lane >> 4, ql = lane & 15;
  int m0 = blockIdx.y * 128, n0 = blockIdx.x * 128;

  f32x4 acc[4][4];
  const f32x4 zero4 = {0.f, 0.f, 0.f, 0.f};
#pragma unroll
  for (int i = 0; i < 4; i++)
#pragma unroll
    for (int j = 0; j < 4; j++) acc[i][j] = zero4;

  for (int k0 = 0; k0 < K; k0 += 32) {
    __syncthreads();
#pragma unroll
    for (int r = 0; r < 2; r++) {
      int idx = r * 256 + tid;
      int row = idx >> 2, ch = idx & 3;
      int am = m0 + row; am = (am < M) ? am : (M - 1);
      gl_lds16(A + (size_t)am * K + k0 + ch * 8, &As[idx * 8]);
      gl_lds16(W + (size_t)(n0 + row) * K + k0 + ch * 8, &Ws[idx * 8]);
    }
    __syncthreads();
    short8 af[4], wf[4];
#pragma unroll
    for (int i = 0; i < 4; i++)
      af[i] = *(const short8*)&As[(wr * 64 + i * 16 + ql) * 32 + q4 * 8];
#pragma unroll
    for (int j = 0; j < 4; j++)
      wf[j] = *(const short8*)&Ws[(wc * 64 + j * 16 + ql) * 32 + q4 * 8];
#pragma unroll
    for (int i = 0; i < 4; i++)
#pragma unroll
      for (int j = 0; j < 4; j++)
        acc[i][j] = __builtin_amdgcn_mfma_f32_16x16x32_bf16(af[i], wf[j], acc[i][j], 0, 0, 0);
  }

  float bb[4];
#pragma unroll
  for (int j = 0; j < 4; j++) bb[j] = bias[n0 + wc * 64 + j * 16 + ql];
#pragma unroll
  for (int i = 0; i < 4; i++) {
#pragma unroll
    for (int rg = 0; rg < 4; rg++) {
      int row = m0 + wr * 64 + i * 16 + q4 * 4 + rg;
      if (row < M) {
#pragma unroll
        for (int j = 0; j < 4; j++) {
          int col = n0 + wc * 64 + j * 16 + ql;
          float v = acc[i][j][rg] + bb[j];
          if (mode == 0) outF[(size_t)row * N + col] = v;
          else           outB[(size_t)row * N + col] = f2bf(v);
        }
      }
    }
  }
}

__global__ __launch_bounds__(256) void gemm_qkv_kernel(
    const unsigned short* __restrict__ xb,
    const unsigned short* __restrict__ wqb, const unsigned short* __restrict__ wkb,
    const unsigned short* __restrict__ wvb,
    const float* __restrict__ bq, const float* __restrict__ bk, const float* __restrict__ bv,
    float* __restrict__ Yq, float* __restrict__ Yk, unsigned short* __restrict__ Vb) {
  int z = blockIdx.z;
  const unsigned short* W = (z == 0) ? wqb : ((z == 1) ? wkb : wvb);
  const float* bias       = (z == 0) ? bq  : ((z == 1) ? bk  : bv);
  float* outF             = (z == 0) ? Yq  : Yk;
  gemm_body(xb, W, bias, outF, Vb, S_TOT, (z == 2) ? 1 : 0);
}

__global__ __launch_bounds__(256) void gemm_out_kernel(
    const unsigned short* __restrict__ AO, const unsigned short* __restrict__ wob,
    const float* __restrict__ bo, float* __restrict__ out) {
  gemm_body(AO, wob, bo, out, nullptr, S_TOT, 0);
}

// ---------------------------------------------------------------------------
// RMSNorm + RoPE. Q pre-scaled by sm_scale*log2(e) -> attn softmax runs in
// exp2 domain with no per-score multiply (rotation is linear -> commutes).
// ---------------------------------------------------------------------------
__global__ __launch_bounds__(256) void normrope_kernel(
    const float* __restrict__ Yq, const float* __restrict__ Yk,
    const float* __restrict__ gq, const float* __restrict__ gk,
    const float* __restrict__ freqs,
    unsigned short* __restrict__ Qb, unsigned short* __restrict__ Kb) {
  int s = blockIdx.x;
  int tid = threadIdx.x;
  int w = tid >> 6, lane = tid & 63;
  const f32x2* yq2 = (const f32x2*)(Yq + (size_t)s * DIM);
  const f32x2* yk2 = (const f32x2*)(Yk + (size_t)s * DIM);
  f32x2 vq[3], vk[3];
  float ssq = 0.f, ssk = 0.f;
#pragma unroll
  for (int r = 0; r < 3; r++) {
    int p = tid + 256 * r;
    vq[r] = yq2[p]; vk[r] = yk2[p];
    ssq += vq[r].x * vq[r].x + vq[r].y * vq[r].y;
    ssk += vk[r].x * vk[r].x + vk[r].y * vk[r].y;
  }
#pragma unroll
  for (int d = 1; d < 64; d <<= 1) {
    ssq += __shfl_xor(ssq, d);
    ssk += __shfl_xor(ssk, d);
  }
  __shared__ float rq[4], rk[4];
  if (lane == 0) { rq[w] = ssq; rk[w] = ssk; }
  __syncthreads();
  float tq = rq[0] + rq[1] + rq[2] + rq[3];
  float tk = rk[0] + rk[1] + rk[2] + rk[3];
  const float SM_L2 = 0.08838834764831845f * 1.4426950408889634f; // scale*log2e
  float invq = rsqrtf(tq * (1.f / DIM) + 1e-6f) * SM_L2;
  float invk = rsqrtf(tk * (1.f / DIM) + 1e-6f);

  int fi = s / (26 * 48);
  int hi = (s / 48) % 26;
  int wi = s % 48;
#pragma unroll
  for (int r = 0; r < 3; r++) {
    int p = tid + 256 * r;
    int c = p & 63;
    int frow = (c < 22) ? fi : ((c < 43) ? hi : wi);
    float ang = freqs[frow * 64 + c];
    float sn, cs;
    __sincosf(ang, &sn, &cs);
    {
      float a = vq[r].x * invq * gq[2 * p];
      float b = vq[r].y * invq * gq[2 * p + 1];
      ushort2 o; o.x = f2bf(a * cs - b * sn); o.y = f2bf(a * sn + b * cs);
      ((ushort2*)Qb)[(size_t)s * (DIM / 2) + p] = o;
    }
    {
      float a = vk[r].x * invk * gk[2 * p];
      float b = vk[r].y * invk * gk[2 * p + 1];
      ushort2 o; o.x = f2bf(a * cs - b * sn); o.y = f2bf(a * sn + b * cs);
      ((ushort2*)Kb)[(size_t)s * (DIM / 2) + p] = o;
    }
  }
}

// ---------------------------------------------------------------------------
// V transpose (unchanged, proven)
// ---------------------------------------------------------------------------
__global__ __launch_bounds__(256) void vtrans_kernel(const unsigned short* __restrict__ Vb,
                                                     unsigned short* __restrict__ Vt) {
  int d0 = blockIdx.x * 64, s0 = blockIdx.y * 64;
  __shared__ unsigned short t[64][65];
  int tid = threadIdx.x;
#pragma unroll
  for (int r = 0; r < 4; r++) {
    int idx = r * 256 + tid;
    int sr = idx >> 4, c4 = (idx & 15) * 4;
    ushort4 v; v.x = v.y = v.z = v.w = 0;
    int s = s0 + sr;
    if (s < S_TOT) v = *(const ushort4*)(Vb + (size_t)s * DIM + d0 + c4);
    t[sr][c4 + 0] = v.x; t[sr][c4 + 1] = v.y; t[sr][c4 + 2] = v.z; t[sr][c4 + 3] = v.w;
  }
  __syncthreads();
#pragma unroll
  for (int r = 0; r < 4; r++) {
    int idx = r * 256 + tid;
    int dr = idx >> 4, s4 = (idx & 15) * 4;
    if (s0 + s4 < S_TOT) {
      ushort4 v;
      v.x = t[s4 + 0][dr]; v.y = t[s4 + 1][dr]; v.z = t[s4 + 2][dr]; v.w = t[s4 + 3][dr];
      *(ushort4*)(Vt + (size_t)(d0 + dr) * S_TOT + s0 + s4) = v;
    }
  }
}

// ---------------------------------------------------------------------------
// Flash attention v10: 32x32x16 MFMA, in-register P, 4 waves x 32q = 128q/block.
// K double-buffered (2x16K), V single-buffered (16K) -> LDS 48KB, 3 blocks/CU.
// Per tile t: barrier; issue V(t), K(t+1); vmcnt(4) [K(t) landed]; barrier;
//   QK^T+softmax+P-pack; vmcnt(2) [V(t) landed]; barrier; PV.
// V(t) staging latency hides under QK^T+softmax. split-K=2, grid 720.
// Inactive tail waves execute all barriers (compute wact-guarded, no continue).
// ---------------------------------------------------------------------------
__global__ __launch_bounds__(256, 3) void attn_kernel(
    const unsigned short* __restrict__ Qb, const unsigned short* __restrict__ Kb,
    const unsigned short* __restrict__ Vt,
    float* __restrict__ Opart, float2* __restrict__ Ml,
    const int* __restrict__ seq_lens) {
  // bijective XCD-chunked remap (T1/m204): 720 % 8 == 0 -> chunks of 90
  // (3 (h,split) K/V groups of ~1MB per XCD L2 -- verified FETCH 23MB in R6).
  const int NWG = QT2 * NHEAD * KSPLIT;    // 720
  int bid = blockIdx.x;
  int xcd = bid & 7, bix = bid >> 3;
  const int qc = NWG >> 3;                 // 90
  int wg = xcd * qc + bix;
  int qt  = wg % QT2;
  int rem = wg / QT2;                      // 0..23, consecutive share (h,split)
  int h    = rem >> 1;
  int sidx = rem & 1;
  int tbeg = sidx ? 30 : 0;
  int tend = sidx ? KVT : 30;

  int tid = threadIdx.x;                   // 0..255
  int wv = tid >> 6, lane = tid & 63;
  int lo = lane & 31, hf = lane >> 5;
  int seqlen = seq_lens[0]; if (seqlen > S_TOT) seqlen = S_TOT;

  __shared__ unsigned short Kl[2][64 * 128];  // 2 x 16 KB, chunk-swizzled
  __shared__ unsigned short Vl[128 * 64];     // 16 KB, chunk-swizzled

  int q0 = qt * 128 + wv * 32;
  bool wact = (q0 < S_TOT);
  const size_t hoff = (size_t)h * HD;

  // K staging: 64 rows x 16 chunks of 8, slot c holds chunk c^(row&15).
  auto stageK = [&](int buf, int t) {
    int k0 = t * 64;
    const unsigned short* kseg = Kb + (size_t)k0 * DIM + hoff;
#pragma unroll
    for (int r = 0; r < 4; r++) {
      int idx = r * 256 + tid;
      int row = idx >> 4, c = idx & 15;
      int g = c ^ (row & 15);
      gl_lds16(kseg + (size_t)row * DIM + g * 8, &Kl[buf][idx * 8]);
    }
  };
  // V staging: 128 d-rows x 8 chunks of 8 keys, slot c holds chunk c^(row&7).
  auto stageV = [&](int t) {
    int k0 = t * 64;
    int kmax = S_TOT - 8 - k0;             // clamp key-chunk start (last tile)
#pragma unroll
    for (int r = 0; r < 4; r++) {
      int idx = r * 256 + tid;
      int row = idx >> 3, c = idx & 7;
      int g = c ^ (row & 7);
      int kc = g * 8; if (kc > kmax) kc = kmax;
      gl_lds16(Vt + (hoff + row) * S_TOT + k0 + kc, &Vl[idx * 8]);
    }
  };

  // Q B-frags (hoisted): qf[ks] = Q[q0+lo][ks*16 + hf*8 .. +7]
  short8 qf[8];
  {
    int qrow = q0 + lo; if (qrow > S_TOT - 1) qrow = S_TOT - 1;
#pragma unroll
    for (int ks = 0; ks < 8; ks++)
      qf[ks] = *(const short8*)(Qb + (size_t)qrow * DIM + hoff + ks * 16 + hf * 8);
  }
  asm volatile("s_waitcnt vmcnt(0)" ::: "memory");  // Q landed; vmcnt clean

  f32x16 o[4];
#pragma unroll
  for (int dq = 0; dq < 4; dq++)
#pragma unroll
    for (int r = 0; r < 16; r++) o[dq][r] = 0.f;
  float m_run = -3.0e38f, l_run = 0.f;

  stageK(0, tbeg);                         // prologue: K(tbeg) in flight (2 ops)

  for (int t = tbeg; t < tend; ++t) {
    int cur = (t - tbeg) & 1;
    int k0 = t * 64;
    __builtin_amdgcn_s_barrier();          // PV(t-1) reads of Vl done
    asm volatile("" ::: "memory");
    stageV(t);                             // V(t) -> Vl (2 ops, lands under QK)
    if (t + 1 < tend) {
      stageK(cur ^ 1, t + 1);              // K(t+1) -> Kl[cur^1] (2 ops)
      asm volatile("s_waitcnt vmcnt(4)" ::: "memory");   // K(t) landed (mine)
    } else {
      asm volatile("s_waitcnt vmcnt(2)" ::: "memory");   // K(t) landed (mine)
    }
    __builtin_amdgcn_sched_barrier(0);
    __builtin_amdgcn_s_barrier();          // K(t) visible to all waves
    asm volatile("" ::: "memory");

    f32x16 s0, s1;
    short8 pa[4];
    if (wact) {
      // ---- QK^T: two 32-key halves, dual accumulation chains ----
#pragma unroll
      for (int r = 0; r < 16; r++) { s0[r] = 0.f; s1[r] = 0.f; }
      __builtin_amdgcn_s_setprio(1);
#pragma unroll
      for (int ks = 0; ks < 8; ks++) {
        int sl = ((ks * 2 + hf) ^ (lo & 15)) * 8;
        short8 kf0 = *(const short8*)&Kl[cur][lo * 128 + sl];
        short8 kf1 = *(const short8*)&Kl[cur][(32 + lo) * 128 + sl];
        s0 = __builtin_amdgcn_mfma_f32_32x32x16_bf16(kf0, qf[ks], s0, 0, 0, 0);
        s1 = __builtin_amdgcn_mfma_f32_32x32x16_bf16(kf1, qf[ks], s1, 0, 0, 0);
      }
      __builtin_amdgcn_s_setprio(0);

      // ---- mask (ragged last tile only) ----
      if (k0 + 64 > seqlen) {
#pragma unroll
        for (int r = 0; r < 16; r++) {
          int key0 = k0 + (r & 3) + 8 * (r >> 2) + 4 * hf;
          if (key0      >= seqlen) s0[r] = -3.0e38f;
          if (key0 + 32 >= seqlen) s1[r] = -3.0e38f;
        }
      }

      // ---- online softmax (exp2 domain; Q pre-scaled) ----
      float mloc = s0[0];
#pragma unroll
      for (int r = 1; r < 16; r++) mloc = fmaxf(mloc, s0[r]);
#pragma unroll
      for (int r = 0; r < 16; r++) mloc = fmaxf(mloc, s1[r]);
      mloc = fmaxf(mloc, __shfl_xor(mloc, 32));

      // defer-max (T13): rescale only when growth > 8 (rare)
      if (!__all(mloc <= m_run + 8.0f)) {
        float mnew = fmaxf(m_run, mloc);
        float alpha = exp2f(m_run - mnew); // 0 on first tile
        m_run = mnew;
        l_run *= alpha;
        int lb = lane & 32;
        float ar[16];
#pragma unroll
        for (int r = 0; r < 16; r++)
          ar[r] = __shfl(alpha, ((r & 3) + 8 * (r >> 2) + 4 * hf) | lb);
#pragma unroll
        for (int dq = 0; dq < 4; dq++)
#pragma unroll
          for (int r = 0; r < 16; r++) o[dq][r] *= ar[r];
      }

      // ---- P = exp2(s - m) -> bf16 A-frags fully in-register (T12) ----
      float lloc = 0.f;
      {
        float p[16];
#pragma unroll
        for (int r = 0; r < 16; r++) { p[r] = exp2f(s0[r] - m_run); lloc += p[r]; }
        unsigned pr[8];
#pragma unroll
        for (int i = 0; i < 8; i++)
          asm("v_cvt_pk_bf16_f32 %0, %1, %2" : "=v"(pr[i]) : "v"(p[2 * i]), "v"(p[2 * i + 1]));
        asm volatile("v_permlane32_swap_b32 %0, %1" : "+v"(pr[0]), "+v"(pr[2]));
        asm volatile("v_permlane32_swap_b32 %0, %1" : "+v"(pr[1]), "+v"(pr[3]));
        asm volatile("v_permlane32_swap_b32 %0, %1" : "+v"(pr[4]), "+v"(pr[6]));
        asm volatile("v_permlane32_swap_b32 %0, %1" : "+v"(pr[5]), "+v"(pr[7]));
        pa[0] = mk8(pr[0], pr[1], pr[2], pr[3]);
        pa[1] = mk8(pr[4], pr[5], pr[6], pr[7]);
      }
      {
        float p[16];
#pragma unroll
        for (int r = 0; r < 16; r++) { p[r] = exp2f(s1[r] - m_run); lloc += p[r]; }
        unsigned pr[8];
#pragma unroll
        for (int i = 0; i < 8; i++)
          asm("v_cvt_pk_bf16_f32 %0, %1, %2" : "=v"(pr[i]) : "v"(p[2 * i]), "v"(p[2 * i + 1]));
        asm volatile("v_permlane32_swap_b32 %0, %1" : "+v"(pr[0]), "+v"(pr[2]));
        asm volatile("v_permlane32_swap_b32 %0, %1" : "+v"(pr[1]), "+v"(pr[3]));
        asm volatile("v_permlane32_swap_b32 %0, %1" : "+v"(pr[4]), "+v"(pr[6]));
        asm volatile("v_permlane32_swap_b32 %0, %1" : "+v"(pr[5]), "+v"(pr[7]));
        pa[2] = mk8(pr[0], pr[1], pr[2], pr[3]);
        pa[3] = mk8(pr[4], pr[5], pr[6], pr[7]);
      }
      lloc += __shfl_xor(lloc, 32);
      l_run += lloc;
    }

    // ---- V(t) landed; visible to all waves ----
    if (t + 1 < tend) {
      asm volatile("s_waitcnt vmcnt(2)" ::: "memory");   // drain V(t), keep K(t+1)
    } else {
      asm volatile("s_waitcnt vmcnt(0)" ::: "memory");
    }
    __builtin_amdgcn_sched_barrier(0);
    __builtin_amdgcn_s_barrier();
    asm volatile("" ::: "memory");

    if (wact) {
      // ---- PV: O[q][d] += P.V, 4 independent acc chains ----
      __builtin_amdgcn_s_setprio(1);
#pragma unroll
      for (int kh2 = 0; kh2 < 4; kh2++) {
        int sl = ((kh2 * 2 + hf) ^ (lo & 7)) * 8;
#pragma unroll
        for (int dq = 0; dq < 4; dq++) {
          short8 vb = *(const short8*)&Vl[(dq * 32 + lo) * 64 + sl];
          o[dq] = __builtin_amdgcn_mfma_f32_32x32x16_bf16(pa[kh2], vb, o[dq], 0, 0, 0);
        }
      }
      __builtin_amdgcn_s_setprio(0);
    }
  }

  if (wact) {
    // unnormalized partials: O f32 [128 q][128 d] + (m,l) per q-row
    size_t ob = (((size_t)sidx * NHEAD + h) * QT2 + qt) * (128 * 128);
#pragma unroll
    for (int dq = 0; dq < 4; dq++)
#pragma unroll
      for (int r = 0; r < 16; r++) {
        int row = wv * 32 + (r & 3) + 8 * (r >> 2) + 4 * hf;
        Opart[ob + (size_t)row * 128 + dq * 32 + lo] = o[dq][r];
      }
    if (lane < 32) {
      float2 ml; ml.x = m_run; ml.y = l_run;
      Ml[((size_t)(sidx * NHEAD + h) * QT2 + qt) * 128 + wv * 32 + lo] = ml;
    }
  }
}

// ---------------------------------------------------------------------------
// split-K reduce: AO[q, h*HD+d] = sum_s w_s O_s / sum_s w_s l_s,
// w_s = exp2(m_s - max_s m_s). Grid exact: NHEAD*S_TOT*HD / 256 = 22464.
// ---------------------------------------------------------------------------
__global__ __launch_bounds__(256) void reduce_kernel(
    const float* __restrict__ Opart, const float2* __restrict__ Ml,
    unsigned short* __restrict__ AO) {
  int flat = blockIdx.x * 256 + threadIdx.x;
  int d = flat & 127;
  int r = flat >> 7;                       // 0 .. NHEAD*S_TOT-1
  int h = r / S_TOT;
  int q = r - h * S_TOT;
  int qt = q >> 7, qi = q & 127;
  size_t ob = (((size_t)h * QT2) + qt) * (128 * 128) + (size_t)qi * 128 + d;
  const size_t so = (size_t)NHEAD * QT2 * 128 * 128;
  int mb = (h * QT2 + qt) * 128 + qi;
  const int sm = NHEAD * QT2 * 128;
  float2 ml0 = Ml[mb], ml1 = Ml[mb + sm];
  float mm = fmaxf(ml0.x, ml1.x);
  float w0 = exp2f(ml0.x - mm), w1 = exp2f(ml1.x - mm);
  float l = w0 * ml0.y + w1 * ml1.y;
  float v = (w0 * Opart[ob] + w1 * Opart[ob + so]) / l;
  AO[(size_t)q * DIM + h * HD + d] = f2bf(v);
}

// ---------------------------------------------------------------------------
extern "C" void kernel_launch(void* const* d_in, const int* in_sizes, int n_in,
                              void* d_out, int out_size, void* d_ws, size_t ws_size,
                              hipStream_t stream) {
  const float* x    = (const float*)d_in[0];
  const float* wq   = (const float*)d_in[1];
  const float* bq   = (const float*)d_in[2];
  const float* wk   = (const float*)d_in[3];
  const float* bk   = (const float*)d_in[4];
  const float* wv   = (const float*)d_in[5];
  const float* bv   = (const float*)d_in[6];
  const float* wo   = (const float*)d_in[7];
  const float* bo   = (const float*)d_in[8];
  const float* gq   = (const float*)d_in[9];
  const float* gk   = (const float*)d_in[10];
  const float* freqs = (const float*)d_in[11];
  const int*   seq  = (const int*)d_in[12];

  char* ws = (char*)d_ws;
  const size_t SZ_X = (size_t)S_TOT * DIM * 2;   // bf16 [S,DIM]
  const size_t SZ_W = (size_t)DIM * DIM * 2;     // bf16 [DIM,DIM]
  const size_t SZ_Y = (size_t)S_TOT * DIM * 4;   // fp32 [S,DIM]

  // Layout (wob hoisted so Yq..wvb form a contiguous region that is dead
  // after normrope -> reused for split-K partials; total ws unchanged):
  size_t off = 0;
  unsigned short* xb  = (unsigned short*)(ws + off); off += SZ_X;
  unsigned short* wob = (unsigned short*)(ws + off); off += SZ_W;
  float*          Yq  = (float*)(ws + off);          off += SZ_Y;
  float*          Yk  = (float*)(ws + off);          off += SZ_Y;
  unsigned short* wqb = (unsigned short*)(ws + off); off += SZ_W;
  unsigned short* wkb = (unsigned short*)(ws + off); off += SZ_W;
  unsigned short* wvb = (unsigned short*)(ws + off); off += SZ_W;
  unsigned short* Vb  = (unsigned short*)(ws + off); off += SZ_X;
  unsigned short* Qb  = (unsigned short*)(ws + off); off += SZ_X;
  unsigned short* Kb  = (unsigned short*)(ws + off); off += SZ_X;
  unsigned short* Vt  = (unsigned short*)(ws + off); off += SZ_X;
  unsigned short* AO  = (unsigned short*)(ws + off); off += SZ_X;

  // split-K partials over the dead Yq..wvb region:
  // 2*12*30*128*128*4 = 47.2 MB + Ml 0.74 MB <= 60.2 MB available
  float*  Opart = (float*)Yq;
  float2* Ml    = (float2*)((char*)Yq +
                  (size_t)KSPLIT * NHEAD * QT2 * 128 * 128 * sizeof(float));

  int total4 = NX4 + 4 * NW4;
  cvt5_kernel<<<dim3((total4 + 255) / 256), 256, 0, stream>>>(
      x, wq, wk, wv, wo, xb, wqb, wkb, wvb, wob);

  gemm_qkv_kernel<<<dim3(DIM / 128, (S_TOT + 127) / 128, 3), 256, 0, stream>>>(
      xb, wqb, wkb, wvb, bq, bk, bv, Yq, Yk, Vb);

  normrope_kernel<<<dim3(S_TOT), 256, 0, stream>>>(Yq, Yk, gq, gk, freqs, Qb, Kb);

  vtrans_kernel<<<dim3(DIM / 64, (S_TOT + 63) / 64), 256, 0, stream>>>(Vb, Vt);

  attn_kernel<<<dim3(QT2 * NHEAD * KSPLIT), 256, 0, stream>>>(
      Qb, Kb, Vt, Opart, Ml, seq);

  reduce_kernel<<<dim3(NHEAD * S_TOT * HD / 256), 256, 0, stream>>>(Opart, Ml, AO);

  gemm_out_kernel<<<dim3(DIM / 128, (S_TOT + 127) / 128), 256, 0, stream>>>(
      AO, wob, bo, (float*)d_out);
}

// Round 9
// 409.031 us; speedup vs baseline: 1.5397x; 1.0884x over previous
//
#include <hip/hip_runtime.h>
#include <stdint.h>

// ---------------------------------------------------------------------------
// ModifiedSelfAttention (Wan block): QKV GEMM -> RMSNorm+RoPE -> flash attn -> O GEMM
// R10: attn reverted to R6 exactly (best verified: 150us, FETCH 23MB).
//      GEMMs: BK 32->64 via dual [128][32] LDS buffers per matrix — every
//      addressing pattern byte-identical to the proven m97-style body, but
//      one barrier-pair now covers 32 MFMA (24 drains instead of 48).
//      LDS 32KB -> occupancy still VGPR-bound ~3 blocks/CU.
// ---------------------------------------------------------------------------

#define DIM   1536
#define S_TOT 3744
#define NHEAD 12
#define HD    128
#define QT2   30          // q-tiles per head (128 q per block)
#define KVT   59          // key tiles of 64 (ceil(3744/64))
#define KSPLIT 2          // split-K factor (tiles [0,30) / [30,59))

using short8 = __attribute__((ext_vector_type(8))) short;   // 8 bf16 (4 VGPRs)
using f32x4  = __attribute__((ext_vector_type(4))) float;   // 16x16 MFMA C/D
using f32x16 = __attribute__((ext_vector_type(16))) float;  // 32x32 MFMA C/D
using f32x2  = __attribute__((ext_vector_type(2))) float;

__device__ __forceinline__ unsigned short f2bf(float f) {
  unsigned u = __builtin_bit_cast(unsigned, f);
  u += 0x7fffu + ((u >> 16) & 1u);     // RNE
  return (unsigned short)(u >> 16);
}

__device__ __forceinline__ short8 mk8(unsigned a, unsigned b, unsigned c, unsigned d) {
  union { unsigned u[4]; short8 s; } x;
  x.u[0] = a; x.u[1] = b; x.u[2] = c; x.u[3] = d;
  return x.s;
}

// async global->LDS, 16B per lane. LDS dest must be wave-uniform base + lane*16.
__device__ __forceinline__ void gl_lds16(const void* g, void* l) {
  auto gp = (const __attribute__((address_space(1))) unsigned int*)g;
  auto lp = (__attribute__((address_space(3))) unsigned int*)(uintptr_t)l;
  __builtin_amdgcn_global_load_lds(gp, lp, 16, 0, 0);
}

// ---------------------------------------------------------------------------
// fp32 -> bf16 convert, all 5 arrays in one launch
// ---------------------------------------------------------------------------
#define NX4 (S_TOT * DIM / 4)
#define NW4 (DIM * DIM / 4)
__global__ __launch_bounds__(256) void cvt5_kernel(
    const float* __restrict__ x, const float* __restrict__ wq,
    const float* __restrict__ wk, const float* __restrict__ wv,
    const float* __restrict__ wo,
    unsigned short* __restrict__ xb, unsigned short* __restrict__ wqb,
    unsigned short* __restrict__ wkb, unsigned short* __restrict__ wvb,
    unsigned short* __restrict__ wob) {
  int gid = blockIdx.x * 256 + threadIdx.x;
  const float* src; unsigned short* dst; int off;
  if (gid < NX4)                { src = x;  dst = xb;  off = gid; }
  else if (gid < NX4 + NW4)     { src = wq; dst = wqb; off = gid - NX4; }
  else if (gid < NX4 + 2 * NW4) { src = wk; dst = wkb; off = gid - NX4 - NW4; }
  else if (gid < NX4 + 3 * NW4) { src = wv; dst = wvb; off = gid - NX4 - 2 * NW4; }
  else if (gid < NX4 + 4 * NW4) { src = wo; dst = wob; off = gid - NX4 - 3 * NW4; }
  else return;
  float4 v = ((const float4*)src)[off];
  ushort4 o;
  o.x = f2bf(v.x); o.y = f2bf(v.y); o.z = f2bf(v.z); o.w = f2bf(v.w);
  ((ushort4*)dst)[off] = o;
}

// ---------------------------------------------------------------------------
// NT GEMM: C[m,n] = sum_k A[m,k]*W[n,k] + bias[n].
// R10: BK=64 as two proven [128][32] sub-buffers; 32 MFMA per barrier-pair.
// ---------------------------------------------------------------------------
__device__ __forceinline__ void gemm_body(const unsigned short* __restrict__ A,
                                          const unsigned short* __restrict__ W,
                                          const float* __restrict__ bias,
                                          float* __restrict__ outF,
                                          unsigned short* __restrict__ outB,
                                          int M, int mode) {
  constexpr int K = DIM, N = DIM;
  __shared__ unsigned short As[2][128 * 32];
  __shared__ unsigned short Ws[2][128 * 32];
  int tid = threadIdx.x;
  int w = tid >> 6, lane = tid & 63;
  int wr = w >> 1, wc = w & 1, q4 = lane >> 4, ql = lane & 15;
  int m0 = blockIdx.y * 128, n0 = blockIdx.x * 128;

  f32x4 acc[4][4];
  const f32x4 zero4 = {0.f, 0.f, 0.f, 0.f};
#pragma unroll
  for (int i = 0; i < 4; i++)
#pragma unroll
    for (int j = 0; j < 4; j++) acc[i][j] = zero4;

  for (int k0 = 0; k0 < K; k0 += 64) {
    __syncthreads();
#pragma unroll
    for (int half = 0; half < 2; half++) {
#pragma unroll
      for (int r = 0; r < 2; r++) {
        int idx = r * 256 + tid;
        int row = idx >> 2, ch = idx & 3;
        int am = m0 + row; am = (am < M) ? am : (M - 1);
        gl_lds16(A + (size_t)am * K + k0 + half * 32 + ch * 8, &As[half][idx * 8]);
        gl_lds16(W + (size_t)(n0 + row) * K + k0 + half * 32 + ch * 8, &Ws[half][idx * 8]);
      }
    }
    __syncthreads();
#pragma unroll
    for (int half = 0; half < 2; half++) {
      short8 af[4], wf[4];
#pragma unroll
      for (int i = 0; i < 4; i++)
        af[i] = *(const short8*)&As[half][(wr * 64 + i * 16 + ql) * 32 + q4 * 8];
#pragma unroll
      for (int j = 0; j < 4; j++)
        wf[j] = *(const short8*)&Ws[half][(wc * 64 + j * 16 + ql) * 32 + q4 * 8];
#pragma unroll
      for (int i = 0; i < 4; i++)
#pragma unroll
        for (int j = 0; j < 4; j++)
          acc[i][j] = __builtin_amdgcn_mfma_f32_16x16x32_bf16(af[i], wf[j], acc[i][j], 0, 0, 0);
    }
  }

  float bb[4];
#pragma unroll
  for (int j = 0; j < 4; j++) bb[j] = bias[n0 + wc * 64 + j * 16 + ql];
#pragma unroll
  for (int i = 0; i < 4; i++) {
#pragma unroll
    for (int rg = 0; rg < 4; rg++) {
      int row = m0 + wr * 64 + i * 16 + q4 * 4 + rg;
      if (row < M) {
#pragma unroll
        for (int j = 0; j < 4; j++) {
          int col = n0 + wc * 64 + j * 16 + ql;
          float v = acc[i][j][rg] + bb[j];
          if (mode == 0) outF[(size_t)row * N + col] = v;
          else           outB[(size_t)row * N + col] = f2bf(v);
        }
      }
    }
  }
}

__global__ __launch_bounds__(256) void gemm_qkv_kernel(
    const unsigned short* __restrict__ xb,
    const unsigned short* __restrict__ wqb, const unsigned short* __restrict__ wkb,
    const unsigned short* __restrict__ wvb,
    const float* __restrict__ bq, const float* __restrict__ bk, const float* __restrict__ bv,
    float* __restrict__ Yq, float* __restrict__ Yk, unsigned short* __restrict__ Vb) {
  int z = blockIdx.z;
  const unsigned short* W = (z == 0) ? wqb : ((z == 1) ? wkb : wvb);
  const float* bias       = (z == 0) ? bq  : ((z == 1) ? bk  : bv);
  float* outF             = (z == 0) ? Yq  : Yk;
  gemm_body(xb, W, bias, outF, Vb, S_TOT, (z == 2) ? 1 : 0);
}

__global__ __launch_bounds__(256) void gemm_out_kernel(
    const unsigned short* __restrict__ AO, const unsigned short* __restrict__ wob,
    const float* __restrict__ bo, float* __restrict__ out) {
  gemm_body(AO, wob, bo, out, nullptr, S_TOT, 0);
}

// ---------------------------------------------------------------------------
// RMSNorm + RoPE. Q pre-scaled by sm_scale*log2(e) -> attn softmax runs in
// exp2 domain with no per-score multiply (rotation is linear -> commutes).
// ---------------------------------------------------------------------------
__global__ __launch_bounds__(256) void normrope_kernel(
    const float* __restrict__ Yq, const float* __restrict__ Yk,
    const float* __restrict__ gq, const float* __restrict__ gk,
    const float* __restrict__ freqs,
    unsigned short* __restrict__ Qb, unsigned short* __restrict__ Kb) {
  int s = blockIdx.x;
  int tid = threadIdx.x;
  int w = tid >> 6, lane = tid & 63;
  const f32x2* yq2 = (const f32x2*)(Yq + (size_t)s * DIM);
  const f32x2* yk2 = (const f32x2*)(Yk + (size_t)s * DIM);
  f32x2 vq[3], vk[3];
  float ssq = 0.f, ssk = 0.f;
#pragma unroll
  for (int r = 0; r < 3; r++) {
    int p = tid + 256 * r;
    vq[r] = yq2[p]; vk[r] = yk2[p];
    ssq += vq[r].x * vq[r].x + vq[r].y * vq[r].y;
    ssk += vk[r].x * vk[r].x + vk[r].y * vk[r].y;
  }
#pragma unroll
  for (int d = 1; d < 64; d <<= 1) {
    ssq += __shfl_xor(ssq, d);
    ssk += __shfl_xor(ssk, d);
  }
  __shared__ float rq[4], rk[4];
  if (lane == 0) { rq[w] = ssq; rk[w] = ssk; }
  __syncthreads();
  float tq = rq[0] + rq[1] + rq[2] + rq[3];
  float tk = rk[0] + rk[1] + rk[2] + rk[3];
  const float SM_L2 = 0.08838834764831845f * 1.4426950408889634f; // scale*log2e
  float invq = rsqrtf(tq * (1.f / DIM) + 1e-6f) * SM_L2;
  float invk = rsqrtf(tk * (1.f / DIM) + 1e-6f);

  int fi = s / (26 * 48);
  int hi = (s / 48) % 26;
  int wi = s % 48;
#pragma unroll
  for (int r = 0; r < 3; r++) {
    int p = tid + 256 * r;
    int c = p & 63;
    int frow = (c < 22) ? fi : ((c < 43) ? hi : wi);
    float ang = freqs[frow * 64 + c];
    float sn, cs;
    __sincosf(ang, &sn, &cs);
    {
      float a = vq[r].x * invq * gq[2 * p];
      float b = vq[r].y * invq * gq[2 * p + 1];
      ushort2 o; o.x = f2bf(a * cs - b * sn); o.y = f2bf(a * sn + b * cs);
      ((ushort2*)Qb)[(size_t)s * (DIM / 2) + p] = o;
    }
    {
      float a = vk[r].x * invk * gk[2 * p];
      float b = vk[r].y * invk * gk[2 * p + 1];
      ushort2 o; o.x = f2bf(a * cs - b * sn); o.y = f2bf(a * sn + b * cs);
      ((ushort2*)Kb)[(size_t)s * (DIM / 2) + p] = o;
    }
  }
}

// ---------------------------------------------------------------------------
// V transpose (unchanged, proven)
// ---------------------------------------------------------------------------
__global__ __launch_bounds__(256) void vtrans_kernel(const unsigned short* __restrict__ Vb,
                                                     unsigned short* __restrict__ Vt) {
  int d0 = blockIdx.x * 64, s0 = blockIdx.y * 64;
  __shared__ unsigned short t[64][65];
  int tid = threadIdx.x;
#pragma unroll
  for (int r = 0; r < 4; r++) {
    int idx = r * 256 + tid;
    int sr = idx >> 4, c4 = (idx & 15) * 4;
    ushort4 v; v.x = v.y = v.z = v.w = 0;
    int s = s0 + sr;
    if (s < S_TOT) v = *(const ushort4*)(Vb + (size_t)s * DIM + d0 + c4);
    t[sr][c4 + 0] = v.x; t[sr][c4 + 1] = v.y; t[sr][c4 + 2] = v.z; t[sr][c4 + 3] = v.w;
  }
  __syncthreads();
#pragma unroll
  for (int r = 0; r < 4; r++) {
    int idx = r * 256 + tid;
    int dr = idx >> 4, s4 = (idx & 15) * 4;
    if (s0 + s4 < S_TOT) {
      ushort4 v;
      v.x = t[s4 + 0][dr]; v.y = t[s4 + 1][dr]; v.z = t[s4 + 2][dr]; v.w = t[s4 + 3][dr];
      *(ushort4*)(Vt + (size_t)(d0 + dr) * S_TOT + s0 + s4) = v;
    }
  }
}

// ---------------------------------------------------------------------------
// Flash attention (R6 verbatim): 32x32x16 MFMA, in-register P,
// 4 waves x 32q = 128q/block, double-buffered K/V (KVBLK=64) with counted
// vmcnt(8), split-K=2, grid 720 (XCD chunks of 90 — verified FETCH 23MB).
// ---------------------------------------------------------------------------
__global__ __launch_bounds__(256, 2) void attn_kernel(
    const unsigned short* __restrict__ Qb, const unsigned short* __restrict__ Kb,
    const unsigned short* __restrict__ Vt,
    float* __restrict__ Opart, float2* __restrict__ Ml,
    const int* __restrict__ seq_lens) {
  const int NWG = QT2 * NHEAD * KSPLIT;    // 720
  int bid = blockIdx.x;
  int xcd = bid & 7, bix = bid >> 3;
  const int qc = NWG >> 3;                 // 90
  int wg = xcd * qc + bix;
  int qt  = wg % QT2;
  int rem = wg / QT2;                      // 0..23, consecutive share (h,split)
  int h    = rem >> 1;
  int sidx = rem & 1;
  int tbeg = sidx ? 30 : 0;
  int tend = sidx ? KVT : 30;

  int tid = threadIdx.x;                   // 0..255
  int wv = tid >> 6, lane = tid & 63;
  int lo = lane & 31, hf = lane >> 5;
  int seqlen = seq_lens[0]; if (seqlen > S_TOT) seqlen = S_TOT;

  __shared__ unsigned short Kl[2][64 * 128];  // 2 x 16 KB, chunk-swizzled
  __shared__ unsigned short Vl[2][128 * 64];  // 2 x 16 KB, chunk-swizzled

  int q0 = qt * 128 + wv * 32;
  bool wact = (q0 < S_TOT);
  const size_t hoff = (size_t)h * HD;

  auto stage = [&](int buf, int t) {
    int k0 = t * 64;
    const unsigned short* kseg = Kb + (size_t)k0 * DIM + hoff;
#pragma unroll
    for (int r = 0; r < 4; r++) {
      int idx = r * 256 + tid;
      int row = idx >> 4, c = idx & 15;
      int g = c ^ (row & 15);
      gl_lds16(kseg + (size_t)row * DIM + g * 8, &Kl[buf][idx * 8]);
    }
    int kmax = S_TOT - 8 - k0;             // clamp key-chunk start (last tile)
#pragma unroll
    for (int r = 0; r < 4; r++) {
      int idx = r * 256 + tid;
      int row = idx >> 3, c = idx & 7;
      int g = c ^ (row & 7);
      int kc = g * 8; if (kc > kmax) kc = kmax;
      gl_lds16(Vt + (hoff + row) * S_TOT + k0 + kc, &Vl[buf][idx * 8]);
    }
  };

  // Q B-frags (hoisted): qf[ks] = Q[q0+lo][ks*16 + hf*8 .. +7]
  short8 qf[8];
  {
    int qrow = q0 + lo; if (qrow > S_TOT - 1) qrow = S_TOT - 1;
#pragma unroll
    for (int ks = 0; ks < 8; ks++)
      qf[ks] = *(const short8*)(Qb + (size_t)qrow * DIM + hoff + ks * 16 + hf * 8);
  }
  asm volatile("s_waitcnt vmcnt(0)" ::: "memory");  // Q landed; vmcnt clean

  f32x16 o[4];
#pragma unroll
  for (int dq = 0; dq < 4; dq++)
#pragma unroll
    for (int r = 0; r < 16; r++) o[dq][r] = 0.f;
  float m_run = -3.0e38f, l_run = 0.f;

  stage(0, tbeg);                          // prologue: first tile in flight

  for (int t = tbeg; t < tend; ++t) {
    int cur = (t - tbeg) & 1;
    int k0 = t * 64;
    __builtin_amdgcn_s_barrier();          // all reads of buf[cur^1] done
    asm volatile("" ::: "memory");
    if (t + 1 < tend) {
      stage(cur ^ 1, t + 1);               // prefetch next tile (8 gl_lds/thr)
      asm volatile("s_waitcnt vmcnt(8)" ::: "memory");   // tile t landed (mine)
    } else {
      asm volatile("s_waitcnt vmcnt(0)" ::: "memory");
    }
    __builtin_amdgcn_sched_barrier(0);
    __builtin_amdgcn_s_barrier();          // tile t landed (everyone)
    asm volatile("" ::: "memory");
    if (!wact) continue;

    // ---- QK^T: two 32-key halves, dual accumulation chains ----
    f32x16 s0, s1;
#pragma unroll
    for (int r = 0; r < 16; r++) { s0[r] = 0.f; s1[r] = 0.f; }
    __builtin_amdgcn_s_setprio(1);
#pragma unroll
    for (int ks = 0; ks < 8; ks++) {
      int sl = ((ks * 2 + hf) ^ (lo & 15)) * 8;
      short8 kf0 = *(const short8*)&Kl[cur][lo * 128 + sl];
      short8 kf1 = *(const short8*)&Kl[cur][(32 + lo) * 128 + sl];
      s0 = __builtin_amdgcn_mfma_f32_32x32x16_bf16(kf0, qf[ks], s0, 0, 0, 0);
      s1 = __builtin_amdgcn_mfma_f32_32x32x16_bf16(kf1, qf[ks], s1, 0, 0, 0);
    }
    __builtin_amdgcn_s_setprio(0);

    // ---- mask (ragged last tile only) ----
    if (k0 + 64 > seqlen) {
#pragma unroll
      for (int r = 0; r < 16; r++) {
        int key0 = k0 + (r & 3) + 8 * (r >> 2) + 4 * hf;
        if (key0      >= seqlen) s0[r] = -3.0e38f;
        if (key0 + 32 >= seqlen) s1[r] = -3.0e38f;
      }
    }

    // ---- online softmax (exp2 domain; Q pre-scaled) ----
    float mloc = s0[0];
#pragma unroll
    for (int r = 1; r < 16; r++) mloc = fmaxf(mloc, s0[r]);
#pragma unroll
    for (int r = 0; r < 16; r++) mloc = fmaxf(mloc, s1[r]);
    mloc = fmaxf(mloc, __shfl_xor(mloc, 32));

    // defer-max (T13): rescale only when growth > 8 (rare); alpha needs a
    // lane->reg-row redistribution (q=lane&31 -> q=(r&3)+8*(r>>2)+4*hf)
    if (!__all(mloc <= m_run + 8.0f)) {
      float mnew = fmaxf(m_run, mloc);
      float alpha = exp2f(m_run - mnew);   // 0 on first tile
      m_run = mnew;
      l_run *= alpha;
      int lb = lane & 32;
      float ar[16];
#pragma unroll
      for (int r = 0; r < 16; r++)
        ar[r] = __shfl(alpha, ((r & 3) + 8 * (r >> 2) + 4 * hf) | lb);
#pragma unroll
      for (int dq = 0; dq < 4; dq++)
#pragma unroll
        for (int r = 0; r < 16; r++) o[dq][r] *= ar[r];
    }

    // ---- P = exp2(s - m) -> bf16 A-frags fully in-register (T12) ----
    float lloc = 0.f;
    short8 pa[4];
    {
      float p[16];
#pragma unroll
      for (int r = 0; r < 16; r++) { p[r] = exp2f(s0[r] - m_run); lloc += p[r]; }
      unsigned pr[8];
#pragma unroll
      for (int i = 0; i < 8; i++)
        asm("v_cvt_pk_bf16_f32 %0, %1, %2" : "=v"(pr[i]) : "v"(p[2 * i]), "v"(p[2 * i + 1]));
      asm volatile("v_permlane32_swap_b32 %0, %1" : "+v"(pr[0]), "+v"(pr[2]));
      asm volatile("v_permlane32_swap_b32 %0, %1" : "+v"(pr[1]), "+v"(pr[3]));
      asm volatile("v_permlane32_swap_b32 %0, %1" : "+v"(pr[4]), "+v"(pr[6]));
      asm volatile("v_permlane32_swap_b32 %0, %1" : "+v"(pr[5]), "+v"(pr[7]));
      pa[0] = mk8(pr[0], pr[1], pr[2], pr[3]);
      pa[1] = mk8(pr[4], pr[5], pr[6], pr[7]);
    }
    {
      float p[16];
#pragma unroll
      for (int r = 0; r < 16; r++) { p[r] = exp2f(s1[r] - m_run); lloc += p[r]; }
      unsigned pr[8];
#pragma unroll
      for (int i = 0; i < 8; i++)
        asm("v_cvt_pk_bf16_f32 %0, %1, %2" : "=v"(pr[i]) : "v"(p[2 * i]), "v"(p[2 * i + 1]));
      asm volatile("v_permlane32_swap_b32 %0, %1" : "+v"(pr[0]), "+v"(pr[2]));
      asm volatile("v_permlane32_swap_b32 %0, %1" : "+v"(pr[1]), "+v"(pr[3]));
      asm volatile("v_permlane32_swap_b32 %0, %1" : "+v"(pr[4]), "+v"(pr[6]));
      asm volatile("v_permlane32_swap_b32 %0, %1" : "+v"(pr[5]), "+v"(pr[7]));
      pa[2] = mk8(pr[0], pr[1], pr[2], pr[3]);
      pa[3] = mk8(pr[4], pr[5], pr[6], pr[7]);
    }
    lloc += __shfl_xor(lloc, 32);
    l_run += lloc;

    // ---- PV: O[q][d] += P.V, 4 independent acc chains ----
    __builtin_amdgcn_s_setprio(1);
#pragma unroll
    for (int kh2 = 0; kh2 < 4; kh2++) {
      int sl = ((kh2 * 2 + hf) ^ (lo & 7)) * 8;
#pragma unroll
      for (int dq = 0; dq < 4; dq++) {
        short8 vb = *(const short8*)&Vl[cur][(dq * 32 + lo) * 64 + sl];
        o[dq] = __builtin_amdgcn_mfma_f32_32x32x16_bf16(pa[kh2], vb, o[dq], 0, 0, 0);
      }
    }
    __builtin_amdgcn_s_setprio(0);
  }

  if (wact) {
    // unnormalized partials: O f32 [128 q][128 d] + (m,l) per q-row
    size_t ob = (((size_t)sidx * NHEAD + h) * QT2 + qt) * (128 * 128);
#pragma unroll
    for (int dq = 0; dq < 4; dq++)
#pragma unroll
      for (int r = 0; r < 16; r++) {
        int row = wv * 32 + (r & 3) + 8 * (r >> 2) + 4 * hf;
        Opart[ob + (size_t)row * 128 + dq * 32 + lo] = o[dq][r];
      }
    if (lane < 32) {
      float2 ml; ml.x = m_run; ml.y = l_run;
      Ml[((size_t)(sidx * NHEAD + h) * QT2 + qt) * 128 + wv * 32 + lo] = ml;
    }
  }
}

// ---------------------------------------------------------------------------
// split-K reduce: AO[q, h*HD+d] = sum_s w_s O_s / sum_s w_s l_s,
// w_s = exp2(m_s - max_s m_s). Grid exact: NHEAD*S_TOT*HD / 256 = 22464.
// ---------------------------------------------------------------------------
__global__ __launch_bounds__(256) void reduce_kernel(
    const float* __restrict__ Opart, const float2* __restrict__ Ml,
    unsigned short* __restrict__ AO) {
  int flat = blockIdx.x * 256 + threadIdx.x;
  int d = flat & 127;
  int r = flat >> 7;                       // 0 .. NHEAD*S_TOT-1
  int h = r / S_TOT;
  int q = r - h * S_TOT;
  int qt = q >> 7, qi = q & 127;
  size_t ob = (((size_t)h * QT2) + qt) * (128 * 128) + (size_t)qi * 128 + d;
  const size_t so = (size_t)NHEAD * QT2 * 128 * 128;
  int mb = (h * QT2 + qt) * 128 + qi;
  const int sm = NHEAD * QT2 * 128;
  float2 ml0 = Ml[mb], ml1 = Ml[mb + sm];
  float mm = fmaxf(ml0.x, ml1.x);
  float w0 = exp2f(ml0.x - mm), w1 = exp2f(ml1.x - mm);
  float l = w0 * ml0.y + w1 * ml1.y;
  float v = (w0 * Opart[ob] + w1 * Opart[ob + so]) / l;
  AO[(size_t)q * DIM + h * HD + d] = f2bf(v);
}

// ---------------------------------------------------------------------------
extern "C" void kernel_launch(void* const* d_in, const int* in_sizes, int n_in,
                              void* d_out, int out_size, void* d_ws, size_t ws_size,
                              hipStream_t stream) {
  const float* x    = (const float*)d_in[0];
  const float* wq   = (const float*)d_in[1];
  const float* bq   = (const float*)d_in[2];
  const float* wk   = (const float*)d_in[3];
  const float* bk   = (const float*)d_in[4];
  const float* wv   = (const float*)d_in[5];
  const float* bv   = (const float*)d_in[6];
  const float* wo   = (const float*)d_in[7];
  const float* bo   = (const float*)d_in[8];
  const float* gq   = (const float*)d_in[9];
  const float* gk   = (const float*)d_in[10];
  const float* freqs = (const float*)d_in[11];
  const int*   seq  = (const int*)d_in[12];

  char* ws = (char*)d_ws;
  const size_t SZ_X = (size_t)S_TOT * DIM * 2;   // bf16 [S,DIM]
  const size_t SZ_W = (size_t)DIM * DIM * 2;     // bf16 [DIM,DIM]
  const size_t SZ_Y = (size_t)S_TOT * DIM * 4;   // fp32 [S,DIM]

  // Layout (wob hoisted so Yq..wvb form a contiguous region that is dead
  // after normrope -> reused for split-K partials; total ws unchanged):
  size_t off = 0;
  unsigned short* xb  = (unsigned short*)(ws + off); off += SZ_X;
  unsigned short* wob = (unsigned short*)(ws + off); off += SZ_W;
  float*          Yq  = (float*)(ws + off);          off += SZ_Y;
  float*          Yk  = (float*)(ws + off);          off += SZ_Y;
  unsigned short* wqb = (unsigned short*)(ws + off); off += SZ_W;
  unsigned short* wkb = (unsigned short*)(ws + off); off += SZ_W;
  unsigned short* wvb = (unsigned short*)(ws + off); off += SZ_W;
  unsigned short* Vb  = (unsigned short*)(ws + off); off += SZ_X;
  unsigned short* Qb  = (unsigned short*)(ws + off); off += SZ_X;
  unsigned short* Kb  = (unsigned short*)(ws + off); off += SZ_X;
  unsigned short* Vt  = (unsigned short*)(ws + off); off += SZ_X;
  unsigned short* AO  = (unsigned short*)(ws + off); off += SZ_X;

  // split-K partials over the dead Yq..wvb region:
  // 2*12*30*128*128*4 = 47.2 MB + Ml 0.74 MB <= 60.2 MB available
  float*  Opart = (float*)Yq;
  float2* Ml    = (float2*)((char*)Yq +
                  (size_t)KSPLIT * NHEAD * QT2 * 128 * 128 * sizeof(float));

  int total4 = NX4 + 4 * NW4;
  cvt5_kernel<<<dim3((total4 + 255) / 256), 256, 0, stream>>>(
      x, wq, wk, wv, wo, xb, wqb, wkb, wvb, wob);

  gemm_qkv_kernel<<<dim3(DIM / 128, (S_TOT + 127) / 128, 3), 256, 0, stream>>>(
      xb, wqb, wkb, wvb, bq, bk, bv, Yq, Yk, Vb);

  normrope_kernel<<<dim3(S_TOT), 256, 0, stream>>>(Yq, Yk, gq, gk, freqs, Qb, Kb);

  vtrans_kernel<<<dim3(DIM / 64, (S_TOT + 63) / 64), 256, 0, stream>>>(Vb, Vt);

  attn_kernel<<<dim3(QT2 * NHEAD * KSPLIT), 256, 0, stream>>>(
      Qb, Kb, Vt, Opart, Ml, seq);

  reduce_kernel<<<dim3(NHEAD * S_TOT * HD / 256), 256, 0, stream>>>(Opart, Ml, AO);

  gemm_out_kernel<<<dim3(DIM / 128, (S_TOT + 127) / 128), 256, 0, stream>>>(
      AO, wob, bo, (float*)d_out);
}

// Round 10
// 401.074 us; speedup vs baseline: 1.5702x; 1.0198x over previous
//
#include <hip/hip_runtime.h>
#include <stdint.h>

// ---------------------------------------------------------------------------
// ModifiedSelfAttention (Wan block): QKV GEMM -> RMSNorm+RoPE -> flash attn -> O GEMM
// R11: R10 + GEMM XCD locality:
//   - both GEMMs launched flat with bijective XCD-chunked swizzle (T1/m204),
//     z folded so each XCD works one W matrix (4.7MB ~ L2) at a time:
//     qkv 1080 = 8 x 135 (one z per chunk), out 360 = 8 x 45.
//   - __launch_bounds__(256,4) on GEMMs (VGPR cap 128, ~115 live; 4 blk/CU).
//   Attn (R6-verified, 150-158us / FETCH 23MB) untouched.
// ---------------------------------------------------------------------------

#define DIM   1536
#define S_TOT 3744
#define NHEAD 12
#define HD    128
#define QT2   30          // q-tiles per head (128 q per block)
#define KVT   59          // key tiles of 64 (ceil(3744/64))
#define KSPLIT 2          // split-K factor (tiles [0,30) / [30,59))

using short8 = __attribute__((ext_vector_type(8))) short;   // 8 bf16 (4 VGPRs)
using f32x4  = __attribute__((ext_vector_type(4))) float;   // 16x16 MFMA C/D
using f32x16 = __attribute__((ext_vector_type(16))) float;  // 32x32 MFMA C/D
using f32x2  = __attribute__((ext_vector_type(2))) float;

__device__ __forceinline__ unsigned short f2bf(float f) {
  unsigned u = __builtin_bit_cast(unsigned, f);
  u += 0x7fffu + ((u >> 16) & 1u);     // RNE
  return (unsigned short)(u >> 16);
}

__device__ __forceinline__ short8 mk8(unsigned a, unsigned b, unsigned c, unsigned d) {
  union { unsigned u[4]; short8 s; } x;
  x.u[0] = a; x.u[1] = b; x.u[2] = c; x.u[3] = d;
  return x.s;
}

// async global->LDS, 16B per lane. LDS dest must be wave-uniform base + lane*16.
__device__ __forceinline__ void gl_lds16(const void* g, void* l) {
  auto gp = (const __attribute__((address_space(1))) unsigned int*)g;
  auto lp = (__attribute__((address_space(3))) unsigned int*)(uintptr_t)l;
  __builtin_amdgcn_global_load_lds(gp, lp, 16, 0, 0);
}

// ---------------------------------------------------------------------------
// fp32 -> bf16 convert, all 5 arrays in one launch
// ---------------------------------------------------------------------------
#define NX4 (S_TOT * DIM / 4)
#define NW4 (DIM * DIM / 4)
__global__ __launch_bounds__(256) void cvt5_kernel(
    const float* __restrict__ x, const float* __restrict__ wq,
    const float* __restrict__ wk, const float* __restrict__ wv,
    const float* __restrict__ wo,
    unsigned short* __restrict__ xb, unsigned short* __restrict__ wqb,
    unsigned short* __restrict__ wkb, unsigned short* __restrict__ wvb,
    unsigned short* __restrict__ wob) {
  int gid = blockIdx.x * 256 + threadIdx.x;
  const float* src; unsigned short* dst; int off;
  if (gid < NX4)                { src = x;  dst = xb;  off = gid; }
  else if (gid < NX4 + NW4)     { src = wq; dst = wqb; off = gid - NX4; }
  else if (gid < NX4 + 2 * NW4) { src = wk; dst = wkb; off = gid - NX4 - NW4; }
  else if (gid < NX4 + 3 * NW4) { src = wv; dst = wvb; off = gid - NX4 - 2 * NW4; }
  else if (gid < NX4 + 4 * NW4) { src = wo; dst = wob; off = gid - NX4 - 3 * NW4; }
  else return;
  float4 v = ((const float4*)src)[off];
  ushort4 o;
  o.x = f2bf(v.x); o.y = f2bf(v.y); o.z = f2bf(v.z); o.w = f2bf(v.w);
  ((ushort4*)dst)[off] = o;
}

// ---------------------------------------------------------------------------
// NT GEMM: C[m,n] = sum_k A[m,k]*W[n,k] + bias[n].
// BK=64 as two proven [128][32] sub-buffers; 32 MFMA per barrier-pair (R10).
// ---------------------------------------------------------------------------
__device__ __forceinline__ void gemm_body(const unsigned short* __restrict__ A,
                                          const unsigned short* __restrict__ W,
                                          const float* __restrict__ bias,
                                          float* __restrict__ outF,
                                          unsigned short* __restrict__ outB,
                                          int M, int mode, int m0, int n0) {
  constexpr int K = DIM, N = DIM;
  __shared__ unsigned short As[2][128 * 32];
  __shared__ unsigned short Ws[2][128 * 32];
  int tid = threadIdx.x;
  int w = tid >> 6, lane = tid & 63;
  int wr = w >> 1, wc = w & 1, q4 = lane >> 4, ql = lane & 15;

  f32x4 acc[4][4];
  const f32x4 zero4 = {0.f, 0.f, 0.f, 0.f};
#pragma unroll
  for (int i = 0; i < 4; i++)
#pragma unroll
    for (int j = 0; j < 4; j++) acc[i][j] = zero4;

  for (int k0 = 0; k0 < K; k0 += 64) {
    __syncthreads();
#pragma unroll
    for (int half = 0; half < 2; half++) {
#pragma unroll
      for (int r = 0; r < 2; r++) {
        int idx = r * 256 + tid;
        int row = idx >> 2, ch = idx & 3;
        int am = m0 + row; am = (am < M) ? am : (M - 1);
        gl_lds16(A + (size_t)am * K + k0 + half * 32 + ch * 8, &As[half][idx * 8]);
        gl_lds16(W + (size_t)(n0 + row) * K + k0 + half * 32 + ch * 8, &Ws[half][idx * 8]);
      }
    }
    __syncthreads();
#pragma unroll
    for (int half = 0; half < 2; half++) {
      short8 af[4], wf[4];
#pragma unroll
      for (int i = 0; i < 4; i++)
        af[i] = *(const short8*)&As[half][(wr * 64 + i * 16 + ql) * 32 + q4 * 8];
#pragma unroll
      for (int j = 0; j < 4; j++)
        wf[j] = *(const short8*)&Ws[half][(wc * 64 + j * 16 + ql) * 32 + q4 * 8];
#pragma unroll
      for (int i = 0; i < 4; i++)
#pragma unroll
        for (int j = 0; j < 4; j++)
          acc[i][j] = __builtin_amdgcn_mfma_f32_16x16x32_bf16(af[i], wf[j], acc[i][j], 0, 0, 0);
    }
  }

  float bb[4];
#pragma unroll
  for (int j = 0; j < 4; j++) bb[j] = bias[n0 + wc * 64 + j * 16 + ql];
#pragma unroll
  for (int i = 0; i < 4; i++) {
#pragma unroll
    for (int rg = 0; rg < 4; rg++) {
      int row = m0 + wr * 64 + i * 16 + q4 * 4 + rg;
      if (row < M) {
#pragma unroll
        for (int j = 0; j < 4; j++) {
          int col = n0 + wc * 64 + j * 16 + ql;
          float v = acc[i][j][rg] + bb[j];
          if (mode == 0) outF[(size_t)row * N + col] = v;
          else           outB[(size_t)row * N + col] = f2bf(v);
        }
      }
    }
  }
}

// qkv: flat grid 1080 = 8 XCD chunks of 135 (= one z, ~11 m-rows x 12 n).
// Each XCD streams ONE 4.7MB W matrix -> L2-resident per chunk.
__global__ __launch_bounds__(256, 4) void gemm_qkv_kernel(
    const unsigned short* __restrict__ xb,
    const unsigned short* __restrict__ wqb, const unsigned short* __restrict__ wkb,
    const unsigned short* __restrict__ wvb,
    const float* __restrict__ bq, const float* __restrict__ bk, const float* __restrict__ bv,
    float* __restrict__ Yq, float* __restrict__ Yk, unsigned short* __restrict__ Vb) {
  const int NWG = 3 * 30 * 12;             // 1080
  int bid = blockIdx.x;
  int xcd = bid & 7, bix = bid >> 3;
  int wg = xcd * (NWG >> 3) + bix;         // chunks of 135
  int z = wg / 360;
  int r = wg - z * 360;
  int m = r / 12, n = r % 12;              // m-major within z: n fastest
  const unsigned short* W = (z == 0) ? wqb : ((z == 1) ? wkb : wvb);
  const float* bias       = (z == 0) ? bq  : ((z == 1) ? bk  : bv);
  float* outF             = (z == 0) ? Yq  : Yk;
  gemm_body(xb, W, bias, outF, Vb, S_TOT, (z == 2) ? 1 : 0, m * 128, n * 128);
}

// out: flat grid 360 = 8 XCD chunks of 45.
__global__ __launch_bounds__(256, 4) void gemm_out_kernel(
    const unsigned short* __restrict__ AO, const unsigned short* __restrict__ wob,
    const float* __restrict__ bo, float* __restrict__ out) {
  const int NWG = 30 * 12;                 // 360
  int bid = blockIdx.x;
  int xcd = bid & 7, bix = bid >> 3;
  int wg = xcd * (NWG >> 3) + bix;         // chunks of 45
  int m = wg / 12, n = wg % 12;
  gemm_body(AO, wob, bo, out, nullptr, S_TOT, 0, m * 128, n * 128);
}

// ---------------------------------------------------------------------------
// RMSNorm + RoPE. Q pre-scaled by sm_scale*log2(e) -> attn softmax runs in
// exp2 domain with no per-score multiply (rotation is linear -> commutes).
// ---------------------------------------------------------------------------
__global__ __launch_bounds__(256) void normrope_kernel(
    const float* __restrict__ Yq, const float* __restrict__ Yk,
    const float* __restrict__ gq, const float* __restrict__ gk,
    const float* __restrict__ freqs,
    unsigned short* __restrict__ Qb, unsigned short* __restrict__ Kb) {
  int s = blockIdx.x;
  int tid = threadIdx.x;
  int w = tid >> 6, lane = tid & 63;
  const f32x2* yq2 = (const f32x2*)(Yq + (size_t)s * DIM);
  const f32x2* yk2 = (const f32x2*)(Yk + (size_t)s * DIM);
  f32x2 vq[3], vk[3];
  float ssq = 0.f, ssk = 0.f;
#pragma unroll
  for (int r = 0; r < 3; r++) {
    int p = tid + 256 * r;
    vq[r] = yq2[p]; vk[r] = yk2[p];
    ssq += vq[r].x * vq[r].x + vq[r].y * vq[r].y;
    ssk += vk[r].x * vk[r].x + vk[r].y * vk[r].y;
  }
#pragma unroll
  for (int d = 1; d < 64; d <<= 1) {
    ssq += __shfl_xor(ssq, d);
    ssk += __shfl_xor(ssk, d);
  }
  __shared__ float rq[4], rk[4];
  if (lane == 0) { rq[w] = ssq; rk[w] = ssk; }
  __syncthreads();
  float tq = rq[0] + rq[1] + rq[2] + rq[3];
  float tk = rk[0] + rk[1] + rk[2] + rk[3];
  const float SM_L2 = 0.08838834764831845f * 1.4426950408889634f; // scale*log2e
  float invq = rsqrtf(tq * (1.f / DIM) + 1e-6f) * SM_L2;
  float invk = rsqrtf(tk * (1.f / DIM) + 1e-6f);

  int fi = s / (26 * 48);
  int hi = (s / 48) % 26;
  int wi = s % 48;
#pragma unroll
  for (int r = 0; r < 3; r++) {
    int p = tid + 256 * r;
    int c = p & 63;
    int frow = (c < 22) ? fi : ((c < 43) ? hi : wi);
    float ang = freqs[frow * 64 + c];
    float sn, cs;
    __sincosf(ang, &sn, &cs);
    {
      float a = vq[r].x * invq * gq[2 * p];
      float b = vq[r].y * invq * gq[2 * p + 1];
      ushort2 o; o.x = f2bf(a * cs - b * sn); o.y = f2bf(a * sn + b * cs);
      ((ushort2*)Qb)[(size_t)s * (DIM / 2) + p] = o;
    }
    {
      float a = vk[r].x * invk * gk[2 * p];
      float b = vk[r].y * invk * gk[2 * p + 1];
      ushort2 o; o.x = f2bf(a * cs - b * sn); o.y = f2bf(a * sn + b * cs);
      ((ushort2*)Kb)[(size_t)s * (DIM / 2) + p] = o;
    }
  }
}

// ---------------------------------------------------------------------------
// V transpose (unchanged, proven)
// ---------------------------------------------------------------------------
__global__ __launch_bounds__(256) void vtrans_kernel(const unsigned short* __restrict__ Vb,
                                                     unsigned short* __restrict__ Vt) {
  int d0 = blockIdx.x * 64, s0 = blockIdx.y * 64;
  __shared__ unsigned short t[64][65];
  int tid = threadIdx.x;
#pragma unroll
  for (int r = 0; r < 4; r++) {
    int idx = r * 256 + tid;
    int sr = idx >> 4, c4 = (idx & 15) * 4;
    ushort4 v; v.x = v.y = v.z = v.w = 0;
    int s = s0 + sr;
    if (s < S_TOT) v = *(const ushort4*)(Vb + (size_t)s * DIM + d0 + c4);
    t[sr][c4 + 0] = v.x; t[sr][c4 + 1] = v.y; t[sr][c4 + 2] = v.z; t[sr][c4 + 3] = v.w;
  }
  __syncthreads();
#pragma unroll
  for (int r = 0; r < 4; r++) {
    int idx = r * 256 + tid;
    int dr = idx >> 4, s4 = (idx & 15) * 4;
    if (s0 + s4 < S_TOT) {
      ushort4 v;
      v.x = t[s4 + 0][dr]; v.y = t[s4 + 1][dr]; v.z = t[s4 + 2][dr]; v.w = t[s4 + 3][dr];
      *(ushort4*)(Vt + (size_t)(d0 + dr) * S_TOT + s0 + s4) = v;
    }
  }
}

// ---------------------------------------------------------------------------
// Flash attention (R6 verbatim): 32x32x16 MFMA, in-register P,
// 4 waves x 32q = 128q/block, double-buffered K/V (KVBLK=64) with counted
// vmcnt(8), split-K=2, grid 720 (XCD chunks of 90 — verified FETCH 23MB).
// ---------------------------------------------------------------------------
__global__ __launch_bounds__(256, 2) void attn_kernel(
    const unsigned short* __restrict__ Qb, const unsigned short* __restrict__ Kb,
    const unsigned short* __restrict__ Vt,
    float* __restrict__ Opart, float2* __restrict__ Ml,
    const int* __restrict__ seq_lens) {
  const int NWG = QT2 * NHEAD * KSPLIT;    // 720
  int bid = blockIdx.x;
  int xcd = bid & 7, bix = bid >> 3;
  const int qc = NWG >> 3;                 // 90
  int wg = xcd * qc + bix;
  int qt  = wg % QT2;
  int rem = wg / QT2;                      // 0..23, consecutive share (h,split)
  int h    = rem >> 1;
  int sidx = rem & 1;
  int tbeg = sidx ? 30 : 0;
  int tend = sidx ? KVT : 30;

  int tid = threadIdx.x;                   // 0..255
  int wv = tid >> 6, lane = tid & 63;
  int lo = lane & 31, hf = lane >> 5;
  int seqlen = seq_lens[0]; if (seqlen > S_TOT) seqlen = S_TOT;

  __shared__ unsigned short Kl[2][64 * 128];  // 2 x 16 KB, chunk-swizzled
  __shared__ unsigned short Vl[2][128 * 64];  // 2 x 16 KB, chunk-swizzled

  int q0 = qt * 128 + wv * 32;
  bool wact = (q0 < S_TOT);
  const size_t hoff = (size_t)h * HD;

  auto stage = [&](int buf, int t) {
    int k0 = t * 64;
    const unsigned short* kseg = Kb + (size_t)k0 * DIM + hoff;
#pragma unroll
    for (int r = 0; r < 4; r++) {
      int idx = r * 256 + tid;
      int row = idx >> 4, c = idx & 15;
      int g = c ^ (row & 15);
      gl_lds16(kseg + (size_t)row * DIM + g * 8, &Kl[buf][idx * 8]);
    }
    int kmax = S_TOT - 8 - k0;             // clamp key-chunk start (last tile)
#pragma unroll
    for (int r = 0; r < 4; r++) {
      int idx = r * 256 + tid;
      int row = idx >> 3, c = idx & 7;
      int g = c ^ (row & 7);
      int kc = g * 8; if (kc > kmax) kc = kmax;
      gl_lds16(Vt + (hoff + row) * S_TOT + k0 + kc, &Vl[buf][idx * 8]);
    }
  };

  // Q B-frags (hoisted): qf[ks] = Q[q0+lo][ks*16 + hf*8 .. +7]
  short8 qf[8];
  {
    int qrow = q0 + lo; if (qrow > S_TOT - 1) qrow = S_TOT - 1;
#pragma unroll
    for (int ks = 0; ks < 8; ks++)
      qf[ks] = *(const short8*)(Qb + (size_t)qrow * DIM + hoff + ks * 16 + hf * 8);
  }
  asm volatile("s_waitcnt vmcnt(0)" ::: "memory");  // Q landed; vmcnt clean

  f32x16 o[4];
#pragma unroll
  for (int dq = 0; dq < 4; dq++)
#pragma unroll
    for (int r = 0; r < 16; r++) o[dq][r] = 0.f;
  float m_run = -3.0e38f, l_run = 0.f;

  stage(0, tbeg);                          // prologue: first tile in flight

  for (int t = tbeg; t < tend; ++t) {
    int cur = (t - tbeg) & 1;
    int k0 = t * 64;
    __builtin_amdgcn_s_barrier();          // all reads of buf[cur^1] done
    asm volatile("" ::: "memory");
    if (t + 1 < tend) {
      stage(cur ^ 1, t + 1);               // prefetch next tile (8 gl_lds/thr)
      asm volatile("s_waitcnt vmcnt(8)" ::: "memory");   // tile t landed (mine)
    } else {
      asm volatile("s_waitcnt vmcnt(0)" ::: "memory");
    }
    __builtin_amdgcn_sched_barrier(0);
    __builtin_amdgcn_s_barrier();          // tile t landed (everyone)
    asm volatile("" ::: "memory");
    if (!wact) continue;

    // ---- QK^T: two 32-key halves, dual accumulation chains ----
    f32x16 s0, s1;
#pragma unroll
    for (int r = 0; r < 16; r++) { s0[r] = 0.f; s1[r] = 0.f; }
    __builtin_amdgcn_s_setprio(1);
#pragma unroll
    for (int ks = 0; ks < 8; ks++) {
      int sl = ((ks * 2 + hf) ^ (lo & 15)) * 8;
      short8 kf0 = *(const short8*)&Kl[cur][lo * 128 + sl];
      short8 kf1 = *(const short8*)&Kl[cur][(32 + lo) * 128 + sl];
      s0 = __builtin_amdgcn_mfma_f32_32x32x16_bf16(kf0, qf[ks], s0, 0, 0, 0);
      s1 = __builtin_amdgcn_mfma_f32_32x32x16_bf16(kf1, qf[ks], s1, 0, 0, 0);
    }
    __builtin_amdgcn_s_setprio(0);

    // ---- mask (ragged last tile only) ----
    if (k0 + 64 > seqlen) {
#pragma unroll
      for (int r = 0; r < 16; r++) {
        int key0 = k0 + (r & 3) + 8 * (r >> 2) + 4 * hf;
        if (key0      >= seqlen) s0[r] = -3.0e38f;
        if (key0 + 32 >= seqlen) s1[r] = -3.0e38f;
      }
    }

    // ---- online softmax (exp2 domain; Q pre-scaled) ----
    float mloc = s0[0];
#pragma unroll
    for (int r = 1; r < 16; r++) mloc = fmaxf(mloc, s0[r]);
#pragma unroll
    for (int r = 0; r < 16; r++) mloc = fmaxf(mloc, s1[r]);
    mloc = fmaxf(mloc, __shfl_xor(mloc, 32));

    // defer-max (T13): rescale only when growth > 8 (rare); alpha needs a
    // lane->reg-row redistribution (q=lane&31 -> q=(r&3)+8*(r>>2)+4*hf)
    if (!__all(mloc <= m_run + 8.0f)) {
      float mnew = fmaxf(m_run, mloc);
      float alpha = exp2f(m_run - mnew);   // 0 on first tile
      m_run = mnew;
      l_run *= alpha;
      int lb = lane & 32;
      float ar[16];
#pragma unroll
      for (int r = 0; r < 16; r++)
        ar[r] = __shfl(alpha, ((r & 3) + 8 * (r >> 2) + 4 * hf) | lb);
#pragma unroll
      for (int dq = 0; dq < 4; dq++)
#pragma unroll
        for (int r = 0; r < 16; r++) o[dq][r] *= ar[r];
    }

    // ---- P = exp2(s - m) -> bf16 A-frags fully in-register (T12) ----
    float lloc = 0.f;
    short8 pa[4];
    {
      float p[16];
#pragma unroll
      for (int r = 0; r < 16; r++) { p[r] = exp2f(s0[r] - m_run); lloc += p[r]; }
      unsigned pr[8];
#pragma unroll
      for (int i = 0; i < 8; i++)
        asm("v_cvt_pk_bf16_f32 %0, %1, %2" : "=v"(pr[i]) : "v"(p[2 * i]), "v"(p[2 * i + 1]));
      asm volatile("v_permlane32_swap_b32 %0, %1" : "+v"(pr[0]), "+v"(pr[2]));
      asm volatile("v_permlane32_swap_b32 %0, %1" : "+v"(pr[1]), "+v"(pr[3]));
      asm volatile("v_permlane32_swap_b32 %0, %1" : "+v"(pr[4]), "+v"(pr[6]));
      asm volatile("v_permlane32_swap_b32 %0, %1" : "+v"(pr[5]), "+v"(pr[7]));
      pa[0] = mk8(pr[0], pr[1], pr[2], pr[3]);
      pa[1] = mk8(pr[4], pr[5], pr[6], pr[7]);
    }
    {
      float p[16];
#pragma unroll
      for (int r = 0; r < 16; r++) { p[r] = exp2f(s1[r] - m_run); lloc += p[r]; }
      unsigned pr[8];
#pragma unroll
      for (int i = 0; i < 8; i++)
        asm("v_cvt_pk_bf16_f32 %0, %1, %2" : "=v"(pr[i]) : "v"(p[2 * i]), "v"(p[2 * i + 1]));
      asm volatile("v_permlane32_swap_b32 %0, %1" : "+v"(pr[0]), "+v"(pr[2]));
      asm volatile("v_permlane32_swap_b32 %0, %1" : "+v"(pr[1]), "+v"(pr[3]));
      asm volatile("v_permlane32_swap_b32 %0, %1" : "+v"(pr[4]), "+v"(pr[6]));
      asm volatile("v_permlane32_swap_b32 %0, %1" : "+v"(pr[5]), "+v"(pr[7]));
      pa[2] = mk8(pr[0], pr[1], pr[2], pr[3]);
      pa[3] = mk8(pr[4], pr[5], pr[6], pr[7]);
    }
    lloc += __shfl_xor(lloc, 32);
    l_run += lloc;

    // ---- PV: O[q][d] += P.V, 4 independent acc chains ----
    __builtin_amdgcn_s_setprio(1);
#pragma unroll
    for (int kh2 = 0; kh2 < 4; kh2++) {
      int sl = ((kh2 * 2 + hf) ^ (lo & 7)) * 8;
#pragma unroll
      for (int dq = 0; dq < 4; dq++) {
        short8 vb = *(const short8*)&Vl[cur][(dq * 32 + lo) * 64 + sl];
        o[dq] = __builtin_amdgcn_mfma_f32_32x32x16_bf16(pa[kh2], vb, o[dq], 0, 0, 0);
      }
    }
    __builtin_amdgcn_s_setprio(0);
  }

  if (wact) {
    // unnormalized partials: O f32 [128 q][128 d] + (m,l) per q-row
    size_t ob = (((size_t)sidx * NHEAD + h) * QT2 + qt) * (128 * 128);
#pragma unroll
    for (int dq = 0; dq < 4; dq++)
#pragma unroll
      for (int r = 0; r < 16; r++) {
        int row = wv * 32 + (r & 3) + 8 * (r >> 2) + 4 * hf;
        Opart[ob + (size_t)row * 128 + dq * 32 + lo] = o[dq][r];
      }
    if (lane < 32) {
      float2 ml; ml.x = m_run; ml.y = l_run;
      Ml[((size_t)(sidx * NHEAD + h) * QT2 + qt) * 128 + wv * 32 + lo] = ml;
    }
  }
}

// ---------------------------------------------------------------------------
// split-K reduce: AO[q, h*HD+d] = sum_s w_s O_s / sum_s w_s l_s,
// w_s = exp2(m_s - max_s m_s). Grid exact: NHEAD*S_TOT*HD / 256 = 22464.
// ---------------------------------------------------------------------------
__global__ __launch_bounds__(256) void reduce_kernel(
    const float* __restrict__ Opart, const float2* __restrict__ Ml,
    unsigned short* __restrict__ AO) {
  int flat = blockIdx.x * 256 + threadIdx.x;
  int d = flat & 127;
  int r = flat >> 7;                       // 0 .. NHEAD*S_TOT-1
  int h = r / S_TOT;
  int q = r - h * S_TOT;
  int qt = q >> 7, qi = q & 127;
  size_t ob = (((size_t)h * QT2) + qt) * (128 * 128) + (size_t)qi * 128 + d;
  const size_t so = (size_t)NHEAD * QT2 * 128 * 128;
  int mb = (h * QT2 + qt) * 128 + qi;
  const int sm = NHEAD * QT2 * 128;
  float2 ml0 = Ml[mb], ml1 = Ml[mb + sm];
  float mm = fmaxf(ml0.x, ml1.x);
  float w0 = exp2f(ml0.x - mm), w1 = exp2f(ml1.x - mm);
  float l = w0 * ml0.y + w1 * ml1.y;
  float v = (w0 * Opart[ob] + w1 * Opart[ob + so]) / l;
  AO[(size_t)q * DIM + h * HD + d] = f2bf(v);
}

// ---------------------------------------------------------------------------
extern "C" void kernel_launch(void* const* d_in, const int* in_sizes, int n_in,
                              void* d_out, int out_size, void* d_ws, size_t ws_size,
                              hipStream_t stream) {
  const float* x    = (const float*)d_in[0];
  const float* wq   = (const float*)d_in[1];
  const float* bq   = (const float*)d_in[2];
  const float* wk   = (const float*)d_in[3];
  const float* bk   = (const float*)d_in[4];
  const float* wv   = (const float*)d_in[5];
  const float* bv   = (const float*)d_in[6];
  const float* wo   = (const float*)d_in[7];
  const float* bo   = (const float*)d_in[8];
  const float* gq   = (const float*)d_in[9];
  const float* gk   = (const float*)d_in[10];
  const float* freqs = (const float*)d_in[11];
  const int*   seq  = (const int*)d_in[12];

  char* ws = (char*)d_ws;
  const size_t SZ_X = (size_t)S_TOT * DIM * 2;   // bf16 [S,DIM]
  const size_t SZ_W = (size_t)DIM * DIM * 2;     // bf16 [DIM,DIM]
  const size_t SZ_Y = (size_t)S_TOT * DIM * 4;   // fp32 [S,DIM]

  // Layout (wob hoisted so Yq..wvb form a contiguous region that is dead
  // after normrope -> reused for split-K partials; total ws unchanged):
  size_t off = 0;
  unsigned short* xb  = (unsigned short*)(ws + off); off += SZ_X;
  unsigned short* wob = (unsigned short*)(ws + off); off += SZ_W;
  float*          Yq  = (float*)(ws + off);          off += SZ_Y;
  float*          Yk  = (float*)(ws + off);          off += SZ_Y;
  unsigned short* wqb = (unsigned short*)(ws + off); off += SZ_W;
  unsigned short* wkb = (unsigned short*)(ws + off); off += SZ_W;
  unsigned short* wvb = (unsigned short*)(ws + off); off += SZ_W;
  unsigned short* Vb  = (unsigned short*)(ws + off); off += SZ_X;
  unsigned short* Qb  = (unsigned short*)(ws + off); off += SZ_X;
  unsigned short* Kb  = (unsigned short*)(ws + off); off += SZ_X;
  unsigned short* Vt  = (unsigned short*)(ws + off); off += SZ_X;
  unsigned short* AO  = (unsigned short*)(ws + off); off += SZ_X;

  // split-K partials over the dead Yq..wvb region:
  // 2*12*30*128*128*4 = 47.2 MB + Ml 0.74 MB <= 60.2 MB available
  float*  Opart = (float*)Yq;
  float2* Ml    = (float2*)((char*)Yq +
                  (size_t)KSPLIT * NHEAD * QT2 * 128 * 128 * sizeof(float));

  int total4 = NX4 + 4 * NW4;
  cvt5_kernel<<<dim3((total4 + 255) / 256), 256, 0, stream>>>(
      x, wq, wk, wv, wo, xb, wqb, wkb, wvb, wob);

  gemm_qkv_kernel<<<dim3(3 * 30 * 12), 256, 0, stream>>>(
      xb, wqb, wkb, wvb, bq, bk, bv, Yq, Yk, Vb);

  normrope_kernel<<<dim3(S_TOT), 256, 0, stream>>>(Yq, Yk, gq, gk, freqs, Qb, Kb);

  vtrans_kernel<<<dim3(DIM / 64, (S_TOT + 63) / 64), 256, 0, stream>>>(Vb, Vt);

  attn_kernel<<<dim3(QT2 * NHEAD * KSPLIT), 256, 0, stream>>>(
      Qb, Kb, Vt, Opart, Ml, seq);

  reduce_kernel<<<dim3(NHEAD * S_TOT * HD / 256), 256, 0, stream>>>(Opart, Ml, AO);

  gemm_out_kernel<<<dim3(30 * 12), 256, 0, stream>>>(AO, wob, bo, (float*)d_out);
}